// Round 8
// baseline (440.495 us; speedup 1.0000x reference)
//
#include <hip/hip_runtime.h>
#include <hip/hip_fp16.h>
#include <math.h>

#define NN 100000
#define NE 800000
#define ET (NN + NE)   /* 900000 edges incl self-loops */
#define GIN 64
#define CH 32
#define NH 4
#define NG 256
#define SLOPE 0.2f
#define LOG2E 1.44269504088896340736f
#define NB1 ((NN + 255) / 256)   /* 391 scan blocks */

// ---- node transform: XLh = fp16(X@Wl+bl), XRh = fp16(X@Wr+br) ----
// W columns in registers, X tile staged in LDS (f32). Input f32 or fp16.
template<int K, int M, int TPC, int NPB, bool INH>
__global__ __launch_bounds__(256, 2)
void transform_kernel(const void* __restrict__ Xv,
                      const float* __restrict__ Wl, const float* __restrict__ bl,
                      const float* __restrict__ Wr, const float* __restrict__ br,
                      __half* __restrict__ XLh, __half* __restrict__ XRh, int n)
{
    constexpr int KR = K / TPC;            // W regs per thread
    __shared__ float sX[NPB * K];
    const int t   = threadIdx.x;
    const int col = t / TPC;               // 0..2M-1
    const int ks  = t % TPC;
    const int k0  = ks * KR;
    const int cw  = (col < M) ? col : col - M;
    const float* W = (col < M) ? Wl : Wr;
    float wreg[KR];
    #pragma unroll
    for (int k = 0; k < KR; ++k) wreg[k] = W[(size_t)(k0 + k) * M + cw];
    const float bias = (ks == 0) ? ((col < M) ? bl[cw] : br[cw]) : 0.f;
    __half* const outp = (col < M) ? XLh : XRh;

    const int base   = blockIdx.x * NPB;
    const int nvalid = (n - base < NPB) ? (n - base) : NPB;

    // stage X tile (coalesced 16B loads; fp16 input unpacked to f32 in LDS)
    if constexpr (INH) {
        const __half* X = (const __half*)Xv;
        constexpr int QTOT = NPB * K / 8;
        for (int q = t; q < QTOT; q += 256) {
            const int node = q / (K / 8);
            const int qq   = q % (K / 8);
            float4 raw = (node < nvalid)
                             ? *(const float4*)(X + (size_t)(base + node) * K + qq * 8)
                             : make_float4(0.f, 0.f, 0.f, 0.f);
            const __half2* hp = (const __half2*)&raw;
            float* dst = sX + node * K + qq * 8;
            #pragma unroll
            for (int j = 0; j < 4; ++j) {
                float2 f = __half22float2(hp[j]);
                dst[2 * j]     = f.x;
                dst[2 * j + 1] = f.y;
            }
        }
    } else {
        const float* X = (const float*)Xv;
        constexpr int QTOT = NPB * K / 4;
        for (int q = t; q < QTOT; q += 256) {
            const int node = q / (K / 4);
            const int qq   = q % (K / 4);
            float4 v = (node < nvalid)
                           ? *(const float4*)(X + (size_t)(base + node) * K + qq * 4)
                           : make_float4(0.f, 0.f, 0.f, 0.f);
            *(float4*)(sX + node * K + qq * 4) = v;
        }
    }
    __syncthreads();

    for (int nn0 = 0; nn0 < nvalid; nn0 += 2) {
        float acc0 = bias, acc1 = bias;
        const float* x0 = sX + nn0 * K + k0;
        const float* x1 = sX + (nn0 + 1) * K + k0;   // safe: NPB even, zero-filled
        const bool has1 = (nn0 + 1 < nvalid);
        #pragma unroll
        for (int kq = 0; kq < KR / 4; ++kq) {
            const float4 a = *(const float4*)(x0 + kq * 4);
            acc0 = fmaf(a.x, wreg[kq * 4 + 0], acc0);
            acc0 = fmaf(a.y, wreg[kq * 4 + 1], acc0);
            acc0 = fmaf(a.z, wreg[kq * 4 + 2], acc0);
            acc0 = fmaf(a.w, wreg[kq * 4 + 3], acc0);
            const float4 b = *(const float4*)(x1 + kq * 4);
            acc1 = fmaf(b.x, wreg[kq * 4 + 0], acc1);
            acc1 = fmaf(b.y, wreg[kq * 4 + 1], acc1);
            acc1 = fmaf(b.z, wreg[kq * 4 + 2], acc1);
            acc1 = fmaf(b.w, wreg[kq * 4 + 3], acc1);
        }
        if (TPC > 1) {
            #pragma unroll
            for (int off = 1; off < TPC; off <<= 1) {
                acc0 += __shfl_xor(acc0, off);
                acc1 += __shfl_xor(acc1, off);
            }
        }
        if (ks == 0) {
            outp[(size_t)(base + nn0) * M + cw] = __float2half(acc0);
            if (has1) outp[(size_t)(base + nn0 + 1) * M + cw] = __float2half(acc1);
        }
    }
}

// ---- CSR build: histogram of dst ----
__global__ void hist_kernel(const int* __restrict__ edst, int* __restrict__ deg)
{
    int e = blockIdx.x * 256 + threadIdx.x;
    if (e >= ET) return;
    int d = (e < NE) ? edst[e] : (e - NE);
    atomicAdd(deg + d, 1);
}

// ---- 3-kernel exclusive scan ----
__global__ void scan1_kernel(const int* __restrict__ deg, int* __restrict__ rowstart,
                             int* __restrict__ bsum)
{
    __shared__ int lds[256];
    int t = threadIdx.x, idx = blockIdx.x * 256 + t;
    int v = (idx < NN) ? deg[idx] : 0;
    lds[t] = v;
    __syncthreads();
    #pragma unroll
    for (int off = 1; off < 256; off <<= 1) {
        int add = (t >= off) ? lds[t - off] : 0;
        __syncthreads();
        lds[t] += add;
        __syncthreads();
    }
    if (idx < NN) rowstart[idx + 1] = lds[t];
    if (t == 255) bsum[blockIdx.x] = lds[255];
}

__global__ void scan2_kernel(int* __restrict__ bsum)
{
    __shared__ int lds[512];
    int t = threadIdx.x;
    int v = (t < NB1) ? bsum[t] : 0;
    lds[t] = v;
    __syncthreads();
    #pragma unroll
    for (int off = 1; off < 512; off <<= 1) {
        int add = (t >= off) ? lds[t - off] : 0;
        __syncthreads();
        lds[t] += add;
        __syncthreads();
    }
    if (t < NB1) bsum[t] = lds[t] - v;
}

__global__ void scan3_kernel(int* __restrict__ rowstart, const int* __restrict__ bsum)
{
    int idx = blockIdx.x * 256 + threadIdx.x;
    if (idx == 0) rowstart[0] = 0;
    if (idx < NN) rowstart[idx + 1] += bsum[blockIdx.x];
}

// ---- CSR scatter ----
__global__ void scatter_kernel(const int* __restrict__ esrc, const int* __restrict__ edst,
                               const int* __restrict__ rowstart,
                               int* __restrict__ cursor, int* __restrict__ csr_src)
{
    int e = blockIdx.x * 256 + threadIdx.x;
    if (e >= ET) return;
    int s, d;
    if (e < NE) { s = esrc[e]; d = edst[e]; } else { s = e - NE; d = s; }
    int pos = rowstart[d] + atomicAdd(cursor + d, 1);
    csr_src[pos] = s;
}

// ---- layer 1 fused GATv2 (H=4, C=32): one wave per node; edge-pair unrolled,
// branchless base-2 online softmax; fp16 storage, f32 math ----
__global__ void gat1_kernel(const int* __restrict__ rowstart, const int* __restrict__ csr_src,
                            const __half* __restrict__ XLh, const __half* __restrict__ XRh,
                            const float* __restrict__ att, const float* __restrict__ bias,
                            __half* __restrict__ H1h)
{
    int node = blockIdx.x * 4 + (threadIdx.x >> 6);
    if (node >= NN) return;
    const int lane = threadIdx.x & 63;
    const int c0 = lane * 2;
    const float2 xr = __half22float2(*(const __half2*)(XRh + (size_t)node * 128 + c0));
    float2 at = *(const float2*)(att + c0);
    at.x *= LOG2E; at.y *= LOG2E;            // base-2 softmax (exact rescale)
    const int beg = rowstart[node], end = rowstart[node + 1];
    float m = -INFINITY, ssum = 0.f, acc0 = 0.f, acc1 = 0.f;
    int i = beg;
    for (; i + 2 <= end; i += 2) {
        const int s0 = csr_src[i];
        const int s1 = csr_src[i + 1];
        const float2 x0 = __half22float2(*(const __half2*)(XLh + (size_t)s0 * 128 + c0));
        const float2 x1 = __half22float2(*(const __half2*)(XLh + (size_t)s1 * 128 + c0));
        float a0 = x0.x + xr.x; a0 = a0 > 0.f ? a0 : SLOPE * a0;
        float b0 = x0.y + xr.y; b0 = b0 > 0.f ? b0 : SLOPE * b0;
        float a1 = x1.x + xr.x; a1 = a1 > 0.f ? a1 : SLOPE * a1;
        float b1 = x1.y + xr.y; b1 = b1 > 0.f ? b1 : SLOPE * b1;
        float p0 = fmaf(a0, at.x, b0 * at.y);
        float p1 = fmaf(a1, at.x, b1 * at.y);
        p0 += __shfl_xor(p0, 1);  p1 += __shfl_xor(p1, 1);
        p0 += __shfl_xor(p0, 2);  p1 += __shfl_xor(p1, 2);
        p0 += __shfl_xor(p0, 4);  p1 += __shfl_xor(p1, 4);
        p0 += __shfl_xor(p0, 8);  p1 += __shfl_xor(p1, 8);   // per-head logit (log2 units)
        const float mn = fmaxf(m, fmaxf(p0, p1));
        const float sc = exp2f(m - mn);       // exp2(-inf)=0 on first pair
        const float e0 = exp2f(p0 - mn);
        const float e1 = exp2f(p1 - mn);
        ssum = fmaf(ssum, sc, e0 + e1);
        acc0 = fmaf(acc0, sc, fmaf(e0, x0.x, e1 * x1.x));
        acc1 = fmaf(acc1, sc, fmaf(e0, x0.y, e1 * x1.y));
        m = mn;
    }
    if (i < end) {
        const int s0 = csr_src[i];
        const float2 x0 = __half22float2(*(const __half2*)(XLh + (size_t)s0 * 128 + c0));
        float a0 = x0.x + xr.x; a0 = a0 > 0.f ? a0 : SLOPE * a0;
        float b0 = x0.y + xr.y; b0 = b0 > 0.f ? b0 : SLOPE * b0;
        float p0 = fmaf(a0, at.x, b0 * at.y);
        p0 += __shfl_xor(p0, 1);
        p0 += __shfl_xor(p0, 2);
        p0 += __shfl_xor(p0, 4);
        p0 += __shfl_xor(p0, 8);
        const float mn = fmaxf(m, p0);
        const float sc = exp2f(m - mn);
        const float e0 = exp2f(p0 - mn);
        ssum = fmaf(ssum, sc, e0);
        acc0 = fmaf(acc0, sc, e0 * x0.x);
        acc1 = fmaf(acc1, sc, e0 * x0.y);
    }
    const float inv = 1.f / (ssum + 1e-16f);
    float o0 = acc0 * inv + bias[c0];
    float o1 = acc1 * inv + bias[c0 + 1];
    o0 = o0 > 0.f ? o0 : expm1f(o0);
    o1 = o1 > 0.f ? o1 : expm1f(o1);
    *(__half2*)(H1h + (size_t)node * 128 + c0) = __float22half2_rn(make_float2(o0, o1));
}

// ---- layer 2 fused GATv2 (H=1, C=32): half-wave per node ----
__global__ void gat2_kernel(const int* __restrict__ rowstart, const int* __restrict__ csr_src,
                            const __half* __restrict__ XLh, const __half* __restrict__ XRh,
                            const float* __restrict__ att,
                            float* __restrict__ H2)
{
    int node = blockIdx.x * 8 + (threadIdx.x >> 5);
    if (node >= NN) return;
    const int c = threadIdx.x & 31;
    const float xr = __half2float(XRh[(size_t)node * 32 + c]);
    const float at = att[c] * LOG2E;
    const int beg = rowstart[node], end = rowstart[node + 1];
    float m = -INFINITY, ssum = 0.f, acc = 0.f;
    int i = beg;
    for (; i + 2 <= end; i += 2) {
        const int s0 = csr_src[i];
        const int s1 = csr_src[i + 1];
        const float x0 = __half2float(XLh[(size_t)s0 * 32 + c]);
        const float x1 = __half2float(XLh[(size_t)s1 * 32 + c]);
        float v0 = x0 + xr; v0 = v0 > 0.f ? v0 : SLOPE * v0;
        float v1 = x1 + xr; v1 = v1 > 0.f ? v1 : SLOPE * v1;
        float p0 = v0 * at;
        float p1 = v1 * at;
        p0 += __shfl_xor(p0, 1);   p1 += __shfl_xor(p1, 1);
        p0 += __shfl_xor(p0, 2);   p1 += __shfl_xor(p1, 2);
        p0 += __shfl_xor(p0, 4);   p1 += __shfl_xor(p1, 4);
        p0 += __shfl_xor(p0, 8);   p1 += __shfl_xor(p1, 8);
        p0 += __shfl_xor(p0, 16);  p1 += __shfl_xor(p1, 16);
        const float mn = fmaxf(m, fmaxf(p0, p1));
        const float sc = exp2f(m - mn);
        const float e0 = exp2f(p0 - mn);
        const float e1 = exp2f(p1 - mn);
        ssum = fmaf(ssum, sc, e0 + e1);
        acc  = fmaf(acc,  sc, fmaf(e0, x0, e1 * x1));
        m = mn;
    }
    if (i < end) {
        const int s0 = csr_src[i];
        const float x0 = __half2float(XLh[(size_t)s0 * 32 + c]);
        float v0 = x0 + xr; v0 = v0 > 0.f ? v0 : SLOPE * v0;
        float p0 = v0 * at;
        p0 += __shfl_xor(p0, 1);
        p0 += __shfl_xor(p0, 2);
        p0 += __shfl_xor(p0, 4);
        p0 += __shfl_xor(p0, 8);
        p0 += __shfl_xor(p0, 16);
        const float mn = fmaxf(m, p0);
        const float sc = exp2f(m - mn);
        const float e0 = exp2f(p0 - mn);
        ssum = fmaf(ssum, sc, e0);
        acc  = fmaf(acc,  sc, e0 * x0);
    }
    H2[(size_t)node * 32 + c] = acc / (ssum + 1e-16f);
}

// ---- mean-pool (batch sorted: run-length accumulate, then atomic flush) ----
__global__ void pool_kernel(const float* __restrict__ h2, const float* __restrict__ bias2,
                            const int* __restrict__ batch,
                            float* __restrict__ pool, float* __restrict__ cnt)
{
    const int c    = threadIdx.x & 31;
    const int slot = threadIdx.x >> 5;     // 0..7
    const int base = blockIdx.x * 256;
    const float b = bias2[c];
    float acc = 0.f, cacc = 0.f;
    int curg = -1;
    for (int i = slot; i < 256; i += 8) {
        int node = base + i;
        if (node >= NN) break;
        int g = batch[node];
        if (g != curg) {
            if (curg >= 0) {
                atomicAdd(pool + (size_t)curg * 32 + c, acc);
                if (c == 0) atomicAdd(cnt + curg, cacc);
            }
            acc = 0.f; cacc = 0.f; curg = g;
        }
        acc += h2[(size_t)node * 32 + c] + b;
        cacc += 1.f;
    }
    if (curg >= 0) {
        atomicAdd(pool + (size_t)curg * 32 + c, acc);
        if (c == 0) atomicAdd(cnt + curg, cacc);
    }
}

// ---- per-graph head MLP ----
__global__ void head_kernel(const float* __restrict__ pool, const float* __restrict__ cnt,
                            const float* __restrict__ Wh1, const float* __restrict__ bh1,
                            const float* __restrict__ Wh2, const float* __restrict__ bh2,
                            float* __restrict__ out)
{
    int g = blockIdx.x;
    int c = threadIdx.x;      // 0..63
    float partial = 0.f;
    if (c < 32) {
        float invc = 1.f / fmaxf(cnt[g], 1.f);
        float acc = bh1[c];
        #pragma unroll
        for (int k = 0; k < 32; ++k)
            acc = fmaf(pool[g * 32 + k] * invc, Wh1[k * 32 + c], acc);
        float z = fmaxf(acc, 0.f);
        partial = z * Wh2[c];
    }
    #pragma unroll
    for (int off = 32; off >= 1; off >>= 1)
        partial += __shfl_down(partial, off);
    if (c == 0) out[g] = partial + bh2[0];
}

extern "C" void kernel_launch(void* const* d_in, const int* in_sizes, int n_in,
                              void* d_out, int out_size, void* d_ws, size_t ws_size,
                              hipStream_t stream)
{
    const float* x     = (const float*)d_in[0];
    const int*   ei    = (const int*)d_in[1];
    const int*   batch = (const int*)d_in[2];
    const float* Wl1   = (const float*)d_in[3];
    const float* bl1   = (const float*)d_in[4];
    const float* Wr1   = (const float*)d_in[5];
    const float* br1   = (const float*)d_in[6];
    const float* att1  = (const float*)d_in[7];
    const float* bias1 = (const float*)d_in[8];
    const float* Wl2   = (const float*)d_in[9];
    const float* bl2   = (const float*)d_in[10];
    const float* Wr2   = (const float*)d_in[11];
    const float* br2   = (const float*)d_in[12];
    const float* att2  = (const float*)d_in[13];
    const float* bias2 = (const float*)d_in[14];
    const float* Wh1   = (const float*)d_in[15];
    const float* bh1   = (const float*)d_in[16];
    const float* Wh2   = (const float*)d_in[17];
    const float* bh2   = (const float*)d_in[18];
    const int* esrc = ei;
    const int* edst = ei + NE;

    // ---- workspace layout (bytes) ----
    char* wsb = (char*)d_ws;
    __half* xl1h = (__half*)wsb;                               // NN*128*2 = 25.6 MB
    __half* xr1h = (__half*)(wsb + (size_t)NN * 128 * 2);      // NN*128*2 = 25.6 MB
    __half* h1h  = xr1h;                                       // alias (per-row RAW in-wave)
    char* p2 = wsb + (size_t)NN * 128 * 4;
    __half* xl2h = (__half*)p2;                                // NN*32*2 = 6.4 MB
    __half* xr2h = (__half*)(p2 + (size_t)NN * 32 * 2);        // NN*32*2 = 6.4 MB
    float*  h2   = (float*)(p2 + (size_t)NN * 32 * 4);         // NN*32*4 = 12.8 MB
    float*  pool = (float*)(p2 + (size_t)NN * 32 * 8);
    float*  cnt  = pool + (size_t)NG * 32;                     // NG
    int* ib       = (int*)(cnt + NG);
    int* deg      = ib;                                        // NN (reused as cursor)
    int* rowstart = ib + NN;                                   // NN+1
    int* bsum     = ib + 2 * NN + 1;                           // 512
    int* csr_src  = ib + 2 * NN + 1 + 512;                     // ET

    // ---- CSR build ----
    hipMemsetAsync(deg, 0, NN * sizeof(int), stream);
    hipMemsetAsync(pool, 0, (size_t)(NG * 33) * sizeof(float), stream);
    hist_kernel<<<(ET + 255) / 256, 256, 0, stream>>>(edst, deg);
    scan1_kernel<<<NB1, 256, 0, stream>>>(deg, rowstart, bsum);
    scan2_kernel<<<1, 512, 0, stream>>>(bsum);
    scan3_kernel<<<NB1, 256, 0, stream>>>(rowstart, bsum);
    hipMemsetAsync(deg, 0, NN * sizeof(int), stream);   // -> cursor
    scatter_kernel<<<(ET + 255) / 256, 256, 0, stream>>>(esrc, edst, rowstart, deg, csr_src);

    // ---- layer 1 ----
    transform_kernel<64, 128, 1, 64, false><<<(NN + 63) / 64, 256, 0, stream>>>(
        x, Wl1, bl1, Wr1, br1, xl1h, xr1h, NN);
    gat1_kernel<<<(NN + 3) / 4, 256, 0, stream>>>(
        rowstart, csr_src, xl1h, xr1h, att1, bias1, h1h);

    // ---- layer 2 ----
    transform_kernel<128, 32, 4, 64, true><<<(NN + 63) / 64, 256, 0, stream>>>(
        h1h, Wl2, bl2, Wr2, br2, xl2h, xr2h, NN);
    gat2_kernel<<<(NN + 7) / 8, 256, 0, stream>>>(
        rowstart, csr_src, xl2h, xr2h, att2, h2);

    // ---- pool + head ----
    pool_kernel<<<(NN + 255) / 256, 256, 0, stream>>>(h2, bias2, batch, pool, cnt);
    head_kernel<<<NG, 64, 0, stream>>>(pool, cnt, Wh1, bh1, Wh2, bh2, (float*)d_out);
}

// Round 10
// 363.069 us; speedup vs baseline: 1.2133x; 1.2133x over previous
//
#include <hip/hip_runtime.h>
#include <hip/hip_fp16.h>
#include <math.h>

#define NN 100000
#define NE 800000
#define ET (NN + NE)   /* 900000 edges incl self-loops */
#define GIN 64
#define CH 32
#define NH 4
#define NG 256
#define SLOPE 0.2f
#define LOG2E 1.44269504088896340736f
#define NB1 ((NN + 255) / 256)   /* 391 scan blocks */

// ---- node transform: XLh = fp16(X@Wl+bl), XRh = fp16(X@Wr+br) ----
// W columns in registers (CPT=2 cols/thread: each LDS x-read feeds 2*4 FMAs,
// halving ds_read_b128 issue vs CPT=1 — R8 showed that path LDS-issue-bound).
// X tile staged in LDS (f32). threads = (2M/CPT)*TPC*NSUB = 256.
template<int K, int M, int TPC, int CPT, int NSUB, int NPB, bool INH>
__global__ __launch_bounds__(256, 2)
void transform_kernel(const void* __restrict__ Xv,
                      const float* __restrict__ Wl, const float* __restrict__ bl,
                      const float* __restrict__ Wr, const float* __restrict__ br,
                      __half* __restrict__ XLh, __half* __restrict__ XRh, int n)
{
    constexpr int KR   = K / TPC;           // k-slice per thread
    constexpr int NCG  = 2 * M / CPT;       // col groups (XL then XR)
    __shared__ float sX[NPB * K];
    const int t      = threadIdx.x;
    const int ks     = t % TPC;
    const int colgrp = (t / TPC) % NCG;
    const int sub    = t / (TPC * NCG);
    const int k0     = ks * KR;
    const bool isR   = colgrp >= (M / CPT);
    const int cw0    = (colgrp - (isR ? M / CPT : 0)) * CPT;
    const float* W   = isR ? Wr : Wl;
    __half* const outp = isR ? XRh : XLh;
    float wreg[KR][CPT];
    #pragma unroll
    for (int k = 0; k < KR; ++k)
        #pragma unroll
        for (int j = 0; j < CPT; ++j)
            wreg[k][j] = W[(size_t)(k0 + k) * M + cw0 + j];
    float bias[CPT];
    #pragma unroll
    for (int j = 0; j < CPT; ++j)
        bias[j] = (ks == 0) ? (isR ? br[cw0 + j] : bl[cw0 + j]) : 0.f;

    const int base   = blockIdx.x * NPB;
    const int nvalid = (n - base < NPB) ? (n - base) : NPB;

    // stage X tile (coalesced 16B loads; fp16 input unpacked to f32 in LDS)
    if constexpr (INH) {
        const __half* X = (const __half*)Xv;
        constexpr int QTOT = NPB * K / 8;
        for (int q = t; q < QTOT; q += 256) {
            const int node = q / (K / 8);
            const int qq   = q % (K / 8);
            float4 raw = (node < nvalid)
                             ? *(const float4*)(X + (size_t)(base + node) * K + qq * 8)
                             : make_float4(0.f, 0.f, 0.f, 0.f);
            const __half2* hp = (const __half2*)&raw;
            float* dst = sX + node * K + qq * 8;
            #pragma unroll
            for (int j = 0; j < 4; ++j) {
                float2 f = __half22float2(hp[j]);
                dst[2 * j]     = f.x;
                dst[2 * j + 1] = f.y;
            }
        }
    } else {
        const float* X = (const float*)Xv;
        constexpr int QTOT = NPB * K / 4;
        for (int q = t; q < QTOT; q += 256) {
            const int node = q / (K / 4);
            const int qq   = q % (K / 4);
            float4 v = (node < nvalid)
                           ? *(const float4*)(X + (size_t)(base + node) * K + qq * 4)
                           : make_float4(0.f, 0.f, 0.f, 0.f);
            *(float4*)(sX + node * K + qq * 4) = v;
        }
    }
    __syncthreads();

    for (int nn = sub; nn < nvalid; nn += NSUB) {
        float acc[CPT];
        #pragma unroll
        for (int j = 0; j < CPT; ++j) acc[j] = bias[j];
        const float* xp = sX + nn * K + k0;
        #pragma unroll
        for (int kq = 0; kq < KR / 4; ++kq) {
            const float4 a = *(const float4*)(xp + kq * 4);
            #pragma unroll
            for (int j = 0; j < CPT; ++j) {
                acc[j] = fmaf(a.x, wreg[kq * 4 + 0][j], acc[j]);
                acc[j] = fmaf(a.y, wreg[kq * 4 + 1][j], acc[j]);
                acc[j] = fmaf(a.z, wreg[kq * 4 + 2][j], acc[j]);
                acc[j] = fmaf(a.w, wreg[kq * 4 + 3][j], acc[j]);
            }
        }
        if (TPC > 1) {
            #pragma unroll
            for (int off = 1; off < TPC; off <<= 1)
                #pragma unroll
                for (int j = 0; j < CPT; ++j)
                    acc[j] += __shfl_xor(acc[j], off);
        }
        if (ks == 0) {
            // CPT=2: pack pair into one half2 store (cw0 even)
            *(__half2*)(outp + (size_t)(base + nn) * M + cw0) =
                __float22half2_rn(make_float2(acc[0], acc[1]));
        }
    }
}

// ---- CSR build: histogram of dst ----
__global__ void hist_kernel(const int* __restrict__ edst, int* __restrict__ deg)
{
    int e = blockIdx.x * 256 + threadIdx.x;
    if (e >= ET) return;
    int d = (e < NE) ? edst[e] : (e - NE);
    atomicAdd(deg + d, 1);
}

// ---- 3-kernel exclusive scan ----
__global__ void scan1_kernel(const int* __restrict__ deg, int* __restrict__ rowstart,
                             int* __restrict__ bsum)
{
    __shared__ int lds[256];
    int t = threadIdx.x, idx = blockIdx.x * 256 + t;
    int v = (idx < NN) ? deg[idx] : 0;
    lds[t] = v;
    __syncthreads();
    #pragma unroll
    for (int off = 1; off < 256; off <<= 1) {
        int add = (t >= off) ? lds[t - off] : 0;
        __syncthreads();
        lds[t] += add;
        __syncthreads();
    }
    if (idx < NN) rowstart[idx + 1] = lds[t];
    if (t == 255) bsum[blockIdx.x] = lds[255];
}

__global__ void scan2_kernel(int* __restrict__ bsum)
{
    __shared__ int lds[512];
    int t = threadIdx.x;
    int v = (t < NB1) ? bsum[t] : 0;
    lds[t] = v;
    __syncthreads();
    #pragma unroll
    for (int off = 1; off < 512; off <<= 1) {
        int add = (t >= off) ? lds[t - off] : 0;
        __syncthreads();
        lds[t] += add;
        __syncthreads();
    }
    if (t < NB1) bsum[t] = lds[t] - v;
}

__global__ void scan3_kernel(int* __restrict__ rowstart, const int* __restrict__ bsum)
{
    int idx = blockIdx.x * 256 + threadIdx.x;
    if (idx == 0) rowstart[0] = 0;
    if (idx < NN) rowstart[idx + 1] += bsum[blockIdx.x];
}

// ---- CSR scatter ----
__global__ void scatter_kernel(const int* __restrict__ esrc, const int* __restrict__ edst,
                               const int* __restrict__ rowstart,
                               int* __restrict__ cursor, int* __restrict__ csr_src)
{
    int e = blockIdx.x * 256 + threadIdx.x;
    if (e >= ET) return;
    int s, d;
    if (e < NE) { s = esrc[e]; d = edst[e]; } else { s = e - NE; d = s; }
    int pos = rowstart[d] + atomicAdd(cursor + d, 1);
    csr_src[pos] = s;
}

// ---- layer 1 fused GATv2 (H=4, C=32): one wave per node; edge-pair unrolled,
// branchless base-2 online softmax; fp16 storage, f32 math ----
__global__ void gat1_kernel(const int* __restrict__ rowstart, const int* __restrict__ csr_src,
                            const __half* __restrict__ XLh, const __half* __restrict__ XRh,
                            const float* __restrict__ att, const float* __restrict__ bias,
                            __half* __restrict__ H1h)
{
    int node = blockIdx.x * 4 + (threadIdx.x >> 6);
    if (node >= NN) return;
    const int lane = threadIdx.x & 63;
    const int c0 = lane * 2;
    const float2 xr = __half22float2(*(const __half2*)(XRh + (size_t)node * 128 + c0));
    float2 at = *(const float2*)(att + c0);
    at.x *= LOG2E; at.y *= LOG2E;            // base-2 softmax (exact rescale)
    const int beg = rowstart[node], end = rowstart[node + 1];
    float m = -INFINITY, ssum = 0.f, acc0 = 0.f, acc1 = 0.f;
    int i = beg;
    for (; i + 2 <= end; i += 2) {
        const int s0 = csr_src[i];
        const int s1 = csr_src[i + 1];
        const float2 x0 = __half22float2(*(const __half2*)(XLh + (size_t)s0 * 128 + c0));
        const float2 x1 = __half22float2(*(const __half2*)(XLh + (size_t)s1 * 128 + c0));
        float a0 = x0.x + xr.x; a0 = a0 > 0.f ? a0 : SLOPE * a0;
        float b0 = x0.y + xr.y; b0 = b0 > 0.f ? b0 : SLOPE * b0;
        float a1 = x1.x + xr.x; a1 = a1 > 0.f ? a1 : SLOPE * a1;
        float b1 = x1.y + xr.y; b1 = b1 > 0.f ? b1 : SLOPE * b1;
        float p0 = fmaf(a0, at.x, b0 * at.y);
        float p1 = fmaf(a1, at.x, b1 * at.y);
        p0 += __shfl_xor(p0, 1);  p1 += __shfl_xor(p1, 1);
        p0 += __shfl_xor(p0, 2);  p1 += __shfl_xor(p1, 2);
        p0 += __shfl_xor(p0, 4);  p1 += __shfl_xor(p1, 4);
        p0 += __shfl_xor(p0, 8);  p1 += __shfl_xor(p1, 8);   // per-head logit (log2 units)
        const float mn = fmaxf(m, fmaxf(p0, p1));
        const float sc = exp2f(m - mn);       // exp2(-inf)=0 on first pair
        const float e0 = exp2f(p0 - mn);
        const float e1 = exp2f(p1 - mn);
        ssum = fmaf(ssum, sc, e0 + e1);
        acc0 = fmaf(acc0, sc, fmaf(e0, x0.x, e1 * x1.x));
        acc1 = fmaf(acc1, sc, fmaf(e0, x0.y, e1 * x1.y));
        m = mn;
    }
    if (i < end) {
        const int s0 = csr_src[i];
        const float2 x0 = __half22float2(*(const __half2*)(XLh + (size_t)s0 * 128 + c0));
        float a0 = x0.x + xr.x; a0 = a0 > 0.f ? a0 : SLOPE * a0;
        float b0 = x0.y + xr.y; b0 = b0 > 0.f ? b0 : SLOPE * b0;
        float p0 = fmaf(a0, at.x, b0 * at.y);
        p0 += __shfl_xor(p0, 1);
        p0 += __shfl_xor(p0, 2);
        p0 += __shfl_xor(p0, 4);
        p0 += __shfl_xor(p0, 8);
        const float mn = fmaxf(m, p0);
        const float sc = exp2f(m - mn);
        const float e0 = exp2f(p0 - mn);
        ssum = fmaf(ssum, sc, e0);
        acc0 = fmaf(acc0, sc, e0 * x0.x);
        acc1 = fmaf(acc1, sc, e0 * x0.y);
    }
    const float inv = 1.f / (ssum + 1e-16f);
    float o0 = acc0 * inv + bias[c0];
    float o1 = acc1 * inv + bias[c0 + 1];
    o0 = o0 > 0.f ? o0 : expm1f(o0);
    o1 = o1 > 0.f ? o1 : expm1f(o1);
    *(__half2*)(H1h + (size_t)node * 128 + c0) = __float22half2_rn(make_float2(o0, o1));
}

// ---- layer 2 fused GATv2 (H=1, C=32): half-wave per node ----
__global__ void gat2_kernel(const int* __restrict__ rowstart, const int* __restrict__ csr_src,
                            const __half* __restrict__ XLh, const __half* __restrict__ XRh,
                            const float* __restrict__ att,
                            float* __restrict__ H2)
{
    int node = blockIdx.x * 8 + (threadIdx.x >> 5);
    if (node >= NN) return;
    const int c = threadIdx.x & 31;
    const float xr = __half2float(XRh[(size_t)node * 32 + c]);
    const float at = att[c] * LOG2E;
    const int beg = rowstart[node], end = rowstart[node + 1];
    float m = -INFINITY, ssum = 0.f, acc = 0.f;
    int i = beg;
    for (; i + 2 <= end; i += 2) {
        const int s0 = csr_src[i];
        const int s1 = csr_src[i + 1];
        const float x0 = __half2float(XLh[(size_t)s0 * 32 + c]);
        const float x1 = __half2float(XLh[(size_t)s1 * 32 + c]);
        float v0 = x0 + xr; v0 = v0 > 0.f ? v0 : SLOPE * v0;
        float v1 = x1 + xr; v1 = v1 > 0.f ? v1 : SLOPE * v1;
        float p0 = v0 * at;
        float p1 = v1 * at;
        p0 += __shfl_xor(p0, 1);   p1 += __shfl_xor(p1, 1);
        p0 += __shfl_xor(p0, 2);   p1 += __shfl_xor(p1, 2);
        p0 += __shfl_xor(p0, 4);   p1 += __shfl_xor(p1, 4);
        p0 += __shfl_xor(p0, 8);   p1 += __shfl_xor(p1, 8);
        p0 += __shfl_xor(p0, 16);  p1 += __shfl_xor(p1, 16);
        const float mn = fmaxf(m, fmaxf(p0, p1));
        const float sc = exp2f(m - mn);
        const float e0 = exp2f(p0 - mn);
        const float e1 = exp2f(p1 - mn);
        ssum = fmaf(ssum, sc, e0 + e1);
        acc  = fmaf(acc,  sc, fmaf(e0, x0, e1 * x1));
        m = mn;
    }
    if (i < end) {
        const int s0 = csr_src[i];
        const float x0 = __half2float(XLh[(size_t)s0 * 32 + c]);
        float v0 = x0 + xr; v0 = v0 > 0.f ? v0 : SLOPE * v0;
        float p0 = v0 * at;
        p0 += __shfl_xor(p0, 1);
        p0 += __shfl_xor(p0, 2);
        p0 += __shfl_xor(p0, 4);
        p0 += __shfl_xor(p0, 8);
        p0 += __shfl_xor(p0, 16);
        const float mn = fmaxf(m, p0);
        const float sc = exp2f(m - mn);
        const float e0 = exp2f(p0 - mn);
        ssum = fmaf(ssum, sc, e0);
        acc  = fmaf(acc,  sc, e0 * x0);
    }
    H2[(size_t)node * 32 + c] = acc / (ssum + 1e-16f);
}

// ---- mean-pool (batch sorted: run-length accumulate, then atomic flush) ----
__global__ void pool_kernel(const float* __restrict__ h2, const float* __restrict__ bias2,
                            const int* __restrict__ batch,
                            float* __restrict__ pool, float* __restrict__ cnt)
{
    const int c    = threadIdx.x & 31;
    const int slot = threadIdx.x >> 5;     // 0..7
    const int base = blockIdx.x * 256;
    const float b = bias2[c];
    float acc = 0.f, cacc = 0.f;
    int curg = -1;
    for (int i = slot; i < 256; i += 8) {
        int node = base + i;
        if (node >= NN) break;
        int g = batch[node];
        if (g != curg) {
            if (curg >= 0) {
                atomicAdd(pool + (size_t)curg * 32 + c, acc);
                if (c == 0) atomicAdd(cnt + curg, cacc);
            }
            acc = 0.f; cacc = 0.f; curg = g;
        }
        acc += h2[(size_t)node * 32 + c] + b;
        cacc += 1.f;
    }
    if (curg >= 0) {
        atomicAdd(pool + (size_t)curg * 32 + c, acc);
        if (c == 0) atomicAdd(cnt + curg, cacc);
    }
}

// ---- per-graph head MLP ----
__global__ void head_kernel(const float* __restrict__ pool, const float* __restrict__ cnt,
                            const float* __restrict__ Wh1, const float* __restrict__ bh1,
                            const float* __restrict__ Wh2, const float* __restrict__ bh2,
                            float* __restrict__ out)
{
    int g = blockIdx.x;
    int c = threadIdx.x;      // 0..63
    float partial = 0.f;
    if (c < 32) {
        float invc = 1.f / fmaxf(cnt[g], 1.f);
        float acc = bh1[c];
        #pragma unroll
        for (int k = 0; k < 32; ++k)
            acc = fmaf(pool[g * 32 + k] * invc, Wh1[k * 32 + c], acc);
        float z = fmaxf(acc, 0.f);
        partial = z * Wh2[c];
    }
    #pragma unroll
    for (int off = 32; off >= 1; off >>= 1)
        partial += __shfl_down(partial, off);
    if (c == 0) out[g] = partial + bh2[0];
}

extern "C" void kernel_launch(void* const* d_in, const int* in_sizes, int n_in,
                              void* d_out, int out_size, void* d_ws, size_t ws_size,
                              hipStream_t stream)
{
    const float* x     = (const float*)d_in[0];
    const int*   ei    = (const int*)d_in[1];
    const int*   batch = (const int*)d_in[2];
    const float* Wl1   = (const float*)d_in[3];
    const float* bl1   = (const float*)d_in[4];
    const float* Wr1   = (const float*)d_in[5];
    const float* br1   = (const float*)d_in[6];
    const float* att1  = (const float*)d_in[7];
    const float* bias1 = (const float*)d_in[8];
    const float* Wl2   = (const float*)d_in[9];
    const float* bl2   = (const float*)d_in[10];
    const float* Wr2   = (const float*)d_in[11];
    const float* br2   = (const float*)d_in[12];
    const float* att2  = (const float*)d_in[13];
    const float* bias2 = (const float*)d_in[14];
    const float* Wh1   = (const float*)d_in[15];
    const float* bh1   = (const float*)d_in[16];
    const float* Wh2   = (const float*)d_in[17];
    const float* bh2   = (const float*)d_in[18];
    const int* esrc = ei;
    const int* edst = ei + NE;

    // ---- workspace layout (bytes) ----
    char* wsb = (char*)d_ws;
    __half* xl1h = (__half*)wsb;                               // NN*128*2 = 25.6 MB
    __half* xr1h = (__half*)(wsb + (size_t)NN * 128 * 2);      // NN*128*2 = 25.6 MB
    __half* h1h  = xr1h;                                       // alias (per-row RAW in-wave)
    char* p2 = wsb + (size_t)NN * 128 * 4;
    __half* xl2h = (__half*)p2;                                // NN*32*2 = 6.4 MB
    __half* xr2h = (__half*)(p2 + (size_t)NN * 32 * 2);        // NN*32*2 = 6.4 MB
    float*  h2   = (float*)(p2 + (size_t)NN * 32 * 4);         // NN*32*4 = 12.8 MB
    float*  pool = (float*)(p2 + (size_t)NN * 32 * 8);
    float*  cnt  = pool + (size_t)NG * 32;                     // NG
    int* ib       = (int*)(cnt + NG);
    int* deg      = ib;                                        // NN (reused as cursor)
    int* rowstart = ib + NN;                                   // NN+1
    int* bsum     = ib + 2 * NN + 1;                           // 512
    int* csr_src  = ib + 2 * NN + 1 + 512;                     // ET

    // ---- CSR build ----
    hipMemsetAsync(deg, 0, NN * sizeof(int), stream);
    hipMemsetAsync(pool, 0, (size_t)(NG * 33) * sizeof(float), stream);
    hist_kernel<<<(ET + 255) / 256, 256, 0, stream>>>(edst, deg);
    scan1_kernel<<<NB1, 256, 0, stream>>>(deg, rowstart, bsum);
    scan2_kernel<<<1, 512, 0, stream>>>(bsum);
    scan3_kernel<<<NB1, 256, 0, stream>>>(rowstart, bsum);
    hipMemsetAsync(deg, 0, NN * sizeof(int), stream);   // -> cursor
    scatter_kernel<<<(ET + 255) / 256, 256, 0, stream>>>(esrc, edst, rowstart, deg, csr_src);

    // ---- layer 1:  K=64, M=128, TPC=1, CPT=2, NSUB=2 -> 128*1*2=256 threads ----
    transform_kernel<64, 128, 1, 2, 2, 64, false><<<(NN + 63) / 64, 256, 0, stream>>>(
        x, Wl1, bl1, Wr1, br1, xl1h, xr1h, NN);
    gat1_kernel<<<(NN + 3) / 4, 256, 0, stream>>>(
        rowstart, csr_src, xl1h, xr1h, att1, bias1, h1h);

    // ---- layer 2:  K=128, M=32, TPC=4, CPT=2, NSUB=2 -> 32*4*2=256 threads ----
    transform_kernel<128, 32, 4, 2, 2, 64, true><<<(NN + 63) / 64, 256, 0, stream>>>(
        h1h, Wl2, bl2, Wr2, br2, xl2h, xr2h, NN);
    gat2_kernel<<<(NN + 7) / 8, 256, 0, stream>>>(
        rowstart, csr_src, xl2h, xr2h, att2, h2);

    // ---- pool + head ----
    pool_kernel<<<(NN + 255) / 256, 256, 0, stream>>>(h2, bias2, batch, pool, cnt);
    head_kernel<<<NG, 64, 0, stream>>>(pool, cnt, Wh1, bh1, Wh2, bh2, (float*)d_out);
}

// Round 11
// 338.233 us; speedup vs baseline: 1.3023x; 1.0734x over previous
//
#include <hip/hip_runtime.h>
#include <hip/hip_fp16.h>
#include <math.h>

#define NN 100000
#define NE 800000
#define ET (NN + NE)   /* 900000 edges incl self-loops */
#define GIN 64
#define CH 32
#define NH 4
#define NG 256
#define SLOPE 0.2f
#define LOG2E 1.44269504088896340736f
#define NB1 ((NN + 255) / 256)   /* 391 scan blocks */

__device__ __forceinline__ void unpack8(float4 raw, float* x) {
    const __half2* hp = (const __half2*)&raw;
    #pragma unroll
    for (int j = 0; j < 4; ++j) {
        float2 f = __half22float2(hp[j]);
        x[2 * j] = f.x; x[2 * j + 1] = f.y;
    }
}
__device__ __forceinline__ void unpack4(float2 raw, float* x) {
    const __half2* hp = (const __half2*)&raw;
    #pragma unroll
    for (int j = 0; j < 2; ++j) {
        float2 f = __half22float2(hp[j]);
        x[2 * j] = f.x; x[2 * j + 1] = f.y;
    }
}

// ---- node transform: XLh = fp16(X@Wl+bl), XRh = fp16(X@Wr+br) ----
// W columns in registers (CPT=2), X tile staged in LDS (f32).
template<int K, int M, int TPC, int CPT, int NSUB, int NPB, bool INH>
__global__ __launch_bounds__(256, 2)
void transform_kernel(const void* __restrict__ Xv,
                      const float* __restrict__ Wl, const float* __restrict__ bl,
                      const float* __restrict__ Wr, const float* __restrict__ br,
                      __half* __restrict__ XLh, __half* __restrict__ XRh, int n)
{
    constexpr int KR   = K / TPC;
    constexpr int NCG  = 2 * M / CPT;
    __shared__ float sX[NPB * K];
    const int t      = threadIdx.x;
    const int ks     = t % TPC;
    const int colgrp = (t / TPC) % NCG;
    const int sub    = t / (TPC * NCG);
    const int k0     = ks * KR;
    const bool isR   = colgrp >= (M / CPT);
    const int cw0    = (colgrp - (isR ? M / CPT : 0)) * CPT;
    const float* W   = isR ? Wr : Wl;
    __half* const outp = isR ? XRh : XLh;
    float wreg[KR][CPT];
    #pragma unroll
    for (int k = 0; k < KR; ++k)
        #pragma unroll
        for (int j = 0; j < CPT; ++j)
            wreg[k][j] = W[(size_t)(k0 + k) * M + cw0 + j];
    float bias[CPT];
    #pragma unroll
    for (int j = 0; j < CPT; ++j)
        bias[j] = (ks == 0) ? (isR ? br[cw0 + j] : bl[cw0 + j]) : 0.f;

    const int base   = blockIdx.x * NPB;
    const int nvalid = (n - base < NPB) ? (n - base) : NPB;

    if constexpr (INH) {
        const __half* X = (const __half*)Xv;
        constexpr int QTOT = NPB * K / 8;
        for (int q = t; q < QTOT; q += 256) {
            const int node = q / (K / 8);
            const int qq   = q % (K / 8);
            float4 raw = (node < nvalid)
                             ? *(const float4*)(X + (size_t)(base + node) * K + qq * 8)
                             : make_float4(0.f, 0.f, 0.f, 0.f);
            unpack8(raw, sX + node * K + qq * 8);
        }
    } else {
        const float* X = (const float*)Xv;
        constexpr int QTOT = NPB * K / 4;
        for (int q = t; q < QTOT; q += 256) {
            const int node = q / (K / 4);
            const int qq   = q % (K / 4);
            float4 v = (node < nvalid)
                           ? *(const float4*)(X + (size_t)(base + node) * K + qq * 4)
                           : make_float4(0.f, 0.f, 0.f, 0.f);
            *(float4*)(sX + node * K + qq * 4) = v;
        }
    }
    __syncthreads();

    for (int nn = sub; nn < nvalid; nn += NSUB) {
        float acc[CPT];
        #pragma unroll
        for (int j = 0; j < CPT; ++j) acc[j] = bias[j];
        const float* xp = sX + nn * K + k0;
        #pragma unroll
        for (int kq = 0; kq < KR / 4; ++kq) {
            const float4 a = *(const float4*)(xp + kq * 4);
            #pragma unroll
            for (int j = 0; j < CPT; ++j) {
                acc[j] = fmaf(a.x, wreg[kq * 4 + 0][j], acc[j]);
                acc[j] = fmaf(a.y, wreg[kq * 4 + 1][j], acc[j]);
                acc[j] = fmaf(a.z, wreg[kq * 4 + 2][j], acc[j]);
                acc[j] = fmaf(a.w, wreg[kq * 4 + 3][j], acc[j]);
            }
        }
        if (TPC > 1) {
            #pragma unroll
            for (int off = 1; off < TPC; off <<= 1)
                #pragma unroll
                for (int j = 0; j < CPT; ++j)
                    acc[j] += __shfl_xor(acc[j], off);
        }
        if (ks == 0) {
            *(__half2*)(outp + (size_t)(base + nn) * M + cw0) =
                __float22half2_rn(make_float2(acc[0], acc[1]));
        }
    }
}

// ---- CSR build: histogram of dst ----
__global__ void hist_kernel(const int* __restrict__ edst, int* __restrict__ deg)
{
    int e = blockIdx.x * 256 + threadIdx.x;
    if (e >= ET) return;
    int d = (e < NE) ? edst[e] : (e - NE);
    atomicAdd(deg + d, 1);
}

// ---- 3-kernel exclusive scan ----
__global__ void scan1_kernel(const int* __restrict__ deg, int* __restrict__ rowstart,
                             int* __restrict__ bsum)
{
    __shared__ int lds[256];
    int t = threadIdx.x, idx = blockIdx.x * 256 + t;
    int v = (idx < NN) ? deg[idx] : 0;
    lds[t] = v;
    __syncthreads();
    #pragma unroll
    for (int off = 1; off < 256; off <<= 1) {
        int add = (t >= off) ? lds[t - off] : 0;
        __syncthreads();
        lds[t] += add;
        __syncthreads();
    }
    if (idx < NN) rowstart[idx + 1] = lds[t];
    if (t == 255) bsum[blockIdx.x] = lds[255];
}

__global__ void scan2_kernel(int* __restrict__ bsum)
{
    __shared__ int lds[512];
    int t = threadIdx.x;
    int v = (t < NB1) ? bsum[t] : 0;
    lds[t] = v;
    __syncthreads();
    #pragma unroll
    for (int off = 1; off < 512; off <<= 1) {
        int add = (t >= off) ? lds[t - off] : 0;
        __syncthreads();
        lds[t] += add;
        __syncthreads();
    }
    if (t < NB1) bsum[t] = lds[t] - v;
}

__global__ void scan3_kernel(int* __restrict__ rowstart, const int* __restrict__ bsum)
{
    int idx = blockIdx.x * 256 + threadIdx.x;
    if (idx == 0) rowstart[0] = 0;
    if (idx < NN) rowstart[idx + 1] += bsum[blockIdx.x];
}

// ---- CSR scatter ----
__global__ void scatter_kernel(const int* __restrict__ esrc, const int* __restrict__ edst,
                               const int* __restrict__ rowstart,
                               int* __restrict__ cursor, int* __restrict__ csr_src)
{
    int e = blockIdx.x * 256 + threadIdx.x;
    if (e >= ET) return;
    int s, d;
    if (e < NE) { s = esrc[e]; d = edst[e]; } else { s = e - NE; d = s; }
    int pos = rowstart[d] + atomicAdd(cursor + d, 1);
    csr_src[pos] = s;
}

// ---- layer 1 fused GATv2 (H=4, C=32): one wave per node, 4 edge-slots/wave.
// lane = (slot = lane>>4, q = lane&15); lane covers channels 8q..8q+7 (head q>>2).
// Per-head logit: 2-shfl reduce in q-group; online softmax merged across slots. ----
__global__ void gat1_kernel(const int* __restrict__ rowstart, const int* __restrict__ csr_src,
                            const __half* __restrict__ XLh, const __half* __restrict__ XRh,
                            const float* __restrict__ att, const float* __restrict__ bias,
                            __half* __restrict__ H1h)
{
    const int node = blockIdx.x * 4 + (threadIdx.x >> 6);
    if (node >= NN) return;
    const int lane = threadIdx.x & 63;
    const int slot = lane >> 4;
    const int q    = lane & 15;
    const int c0   = q * 8;

    float xr[8], at[8];
    unpack8(*(const float4*)(XRh + (size_t)node * 128 + c0), xr);
    {
        const float4 a0 = *(const float4*)(att + c0);
        const float4 a1 = *(const float4*)(att + c0 + 4);
        at[0] = a0.x * LOG2E; at[1] = a0.y * LOG2E;
        at[2] = a0.z * LOG2E; at[3] = a0.w * LOG2E;
        at[4] = a1.x * LOG2E; at[5] = a1.y * LOG2E;
        at[6] = a1.z * LOG2E; at[7] = a1.w * LOG2E;
    }
    const int beg = rowstart[node], end = rowstart[node + 1];
    float m = -INFINITY, ssum = 0.f;
    float acc[8] = {0.f, 0.f, 0.f, 0.f, 0.f, 0.f, 0.f, 0.f};

    for (int i = beg; i < end; i += 4) {
        const int idx   = i + slot;
        const bool valid = idx < end;
        const int s = valid ? csr_src[idx] : 0;
        float xl[8];
        unpack8(*(const float4*)(XLh + (size_t)s * 128 + c0), xl);
        float p = 0.f;
        #pragma unroll
        for (int j = 0; j < 8; ++j) {
            float v = xl[j] + xr[j];
            v = fmaxf(v, SLOPE * v);          // leaky_relu
            p = fmaf(v, at[j], p);
        }
        p += __shfl_xor(p, 1);
        p += __shfl_xor(p, 2);                // full 32-ch head logit (log2 units)
        if (!valid) p = -INFINITY;
        float pm = fmaxf(p, __shfl_xor(p, 16));
        pm = fmaxf(pm, __shfl_xor(pm, 32));   // max over 4 slots
        const float mn = fmaxf(m, pm);
        const float sc = exp2f(m - mn);       // exp2(-inf)=0 on first iter
        const float e  = exp2f(p - mn);       // 0 for invalid slots
        ssum = fmaf(ssum, sc, e);
        #pragma unroll
        for (int j = 0; j < 8; ++j)
            acc[j] = fmaf(acc[j], sc, e * xl[j]);
        m = mn;
    }
    // merge slots
    ssum += __shfl_xor(ssum, 16);
    ssum += __shfl_xor(ssum, 32);
    #pragma unroll
    for (int j = 0; j < 8; ++j) {
        acc[j] += __shfl_xor(acc[j], 16);
        acc[j] += __shfl_xor(acc[j], 32);
    }
    if (slot == 0) {
        const float inv = 1.f / (ssum + 1e-16f);
        const float4 b0 = *(const float4*)(bias + c0);
        const float4 b1 = *(const float4*)(bias + c0 + 4);
        const float bb[8] = {b0.x, b0.y, b0.z, b0.w, b1.x, b1.y, b1.z, b1.w};
        __half2 outh[4];
        #pragma unroll
        for (int j = 0; j < 4; ++j) {
            float o0 = acc[2 * j] * inv + bb[2 * j];
            float o1 = acc[2 * j + 1] * inv + bb[2 * j + 1];
            o0 = o0 > 0.f ? o0 : expm1f(o0);  // CELU(alpha=1)
            o1 = o1 > 0.f ? o1 : expm1f(o1);
            outh[j] = __float22half2_rn(make_float2(o0, o1));
        }
        *(float4*)(H1h + (size_t)node * 128 + c0) = *(const float4*)outh;
    }
}

// ---- layer 2 fused GATv2 (H=1, C=32): 32 lanes/node, 4 edge-slots.
// l2 = (slot = l2>>3, q = l2&7); lane covers channels 4q..4q+3. ----
__global__ void gat2_kernel(const int* __restrict__ rowstart, const int* __restrict__ csr_src,
                            const __half* __restrict__ XLh, const __half* __restrict__ XRh,
                            const float* __restrict__ att,
                            float* __restrict__ H2)
{
    const int node = blockIdx.x * 8 + (threadIdx.x >> 5);
    if (node >= NN) return;
    const int l2   = threadIdx.x & 31;
    const int slot = l2 >> 3;
    const int q    = l2 & 7;
    const int c0   = q * 4;

    float xr[4], at[4];
    unpack4(*(const float2*)(XRh + (size_t)node * 32 + c0), xr);
    {
        const float4 a = *(const float4*)(att + c0);
        at[0] = a.x * LOG2E; at[1] = a.y * LOG2E;
        at[2] = a.z * LOG2E; at[3] = a.w * LOG2E;
    }
    const int beg = rowstart[node], end = rowstart[node + 1];
    float m = -INFINITY, ssum = 0.f;
    float acc[4] = {0.f, 0.f, 0.f, 0.f};

    for (int i = beg; i < end; i += 4) {
        const int idx   = i + slot;
        const bool valid = idx < end;
        const int s = valid ? csr_src[idx] : 0;
        float xl[4];
        unpack4(*(const float2*)(XLh + (size_t)s * 32 + c0), xl);
        float p = 0.f;
        #pragma unroll
        for (int j = 0; j < 4; ++j) {
            float v = xl[j] + xr[j];
            v = fmaxf(v, SLOPE * v);
            p = fmaf(v, at[j], p);
        }
        p += __shfl_xor(p, 1);
        p += __shfl_xor(p, 2);
        p += __shfl_xor(p, 4);                // full 32-ch logit
        if (!valid) p = -INFINITY;
        float pm = fmaxf(p, __shfl_xor(p, 8));
        pm = fmaxf(pm, __shfl_xor(pm, 16));   // max over 4 slots (stays in 32-group)
        const float mn = fmaxf(m, pm);
        const float sc = exp2f(m - mn);
        const float e  = exp2f(p - mn);
        ssum = fmaf(ssum, sc, e);
        #pragma unroll
        for (int j = 0; j < 4; ++j)
            acc[j] = fmaf(acc[j], sc, e * xl[j]);
        m = mn;
    }
    ssum += __shfl_xor(ssum, 8);
    ssum += __shfl_xor(ssum, 16);
    #pragma unroll
    for (int j = 0; j < 4; ++j) {
        acc[j] += __shfl_xor(acc[j], 8);
        acc[j] += __shfl_xor(acc[j], 16);
    }
    if (slot == 0) {
        const float inv = 1.f / (ssum + 1e-16f);
        float4 o;
        o.x = acc[0] * inv; o.y = acc[1] * inv;
        o.z = acc[2] * inv; o.w = acc[3] * inv;
        *(float4*)(H2 + (size_t)node * 32 + c0) = o;
    }
}

// ---- mean-pool (batch sorted: run-length accumulate, then atomic flush) ----
__global__ void pool_kernel(const float* __restrict__ h2, const float* __restrict__ bias2,
                            const int* __restrict__ batch,
                            float* __restrict__ pool, float* __restrict__ cnt)
{
    const int c    = threadIdx.x & 31;
    const int slot = threadIdx.x >> 5;     // 0..7
    const int base = blockIdx.x * 256;
    const float b = bias2[c];
    float acc = 0.f, cacc = 0.f;
    int curg = -1;
    for (int i = slot; i < 256; i += 8) {
        int node = base + i;
        if (node >= NN) break;
        int g = batch[node];
        if (g != curg) {
            if (curg >= 0) {
                atomicAdd(pool + (size_t)curg * 32 + c, acc);
                if (c == 0) atomicAdd(cnt + curg, cacc);
            }
            acc = 0.f; cacc = 0.f; curg = g;
        }
        acc += h2[(size_t)node * 32 + c] + b;
        cacc += 1.f;
    }
    if (curg >= 0) {
        atomicAdd(pool + (size_t)curg * 32 + c, acc);
        if (c == 0) atomicAdd(cnt + curg, cacc);
    }
}

// ---- per-graph head MLP ----
__global__ void head_kernel(const float* __restrict__ pool, const float* __restrict__ cnt,
                            const float* __restrict__ Wh1, const float* __restrict__ bh1,
                            const float* __restrict__ Wh2, const float* __restrict__ bh2,
                            float* __restrict__ out)
{
    int g = blockIdx.x;
    int c = threadIdx.x;      // 0..63
    float partial = 0.f;
    if (c < 32) {
        float invc = 1.f / fmaxf(cnt[g], 1.f);
        float acc = bh1[c];
        #pragma unroll
        for (int k = 0; k < 32; ++k)
            acc = fmaf(pool[g * 32 + k] * invc, Wh1[k * 32 + c], acc);
        float z = fmaxf(acc, 0.f);
        partial = z * Wh2[c];
    }
    #pragma unroll
    for (int off = 32; off >= 1; off >>= 1)
        partial += __shfl_down(partial, off);
    if (c == 0) out[g] = partial + bh2[0];
}

extern "C" void kernel_launch(void* const* d_in, const int* in_sizes, int n_in,
                              void* d_out, int out_size, void* d_ws, size_t ws_size,
                              hipStream_t stream)
{
    const float* x     = (const float*)d_in[0];
    const int*   ei    = (const int*)d_in[1];
    const int*   batch = (const int*)d_in[2];
    const float* Wl1   = (const float*)d_in[3];
    const float* bl1   = (const float*)d_in[4];
    const float* Wr1   = (const float*)d_in[5];
    const float* br1   = (const float*)d_in[6];
    const float* att1  = (const float*)d_in[7];
    const float* bias1 = (const float*)d_in[8];
    const float* Wl2   = (const float*)d_in[9];
    const float* bl2   = (const float*)d_in[10];
    const float* Wr2   = (const float*)d_in[11];
    const float* br2   = (const float*)d_in[12];
    const float* att2  = (const float*)d_in[13];
    const float* bias2 = (const float*)d_in[14];
    const float* Wh1   = (const float*)d_in[15];
    const float* bh1   = (const float*)d_in[16];
    const float* Wh2   = (const float*)d_in[17];
    const float* bh2   = (const float*)d_in[18];
    const int* esrc = ei;
    const int* edst = ei + NE;

    // ---- workspace layout (bytes) ----
    char* wsb = (char*)d_ws;
    __half* xl1h = (__half*)wsb;                               // NN*128*2
    __half* xr1h = (__half*)(wsb + (size_t)NN * 128 * 2);      // NN*128*2
    __half* h1h  = xr1h;                                       // alias (per-row RAW in-wave)
    char* p2 = wsb + (size_t)NN * 128 * 4;
    __half* xl2h = (__half*)p2;                                // NN*32*2
    __half* xr2h = (__half*)(p2 + (size_t)NN * 32 * 2);        // NN*32*2
    float*  h2   = (float*)(p2 + (size_t)NN * 32 * 4);         // NN*32*4
    float*  pool = (float*)(p2 + (size_t)NN * 32 * 8);
    float*  cnt  = pool + (size_t)NG * 32;                     // NG
    int* ib       = (int*)(cnt + NG);
    int* deg      = ib;                                        // NN (reused as cursor)
    int* rowstart = ib + NN;                                   // NN+1
    int* bsum     = ib + 2 * NN + 1;                           // 512
    int* csr_src  = ib + 2 * NN + 1 + 512;                     // ET

    // ---- CSR build ----
    hipMemsetAsync(deg, 0, NN * sizeof(int), stream);
    hipMemsetAsync(pool, 0, (size_t)(NG * 33) * sizeof(float), stream);
    hist_kernel<<<(ET + 255) / 256, 256, 0, stream>>>(edst, deg);
    scan1_kernel<<<NB1, 256, 0, stream>>>(deg, rowstart, bsum);
    scan2_kernel<<<1, 512, 0, stream>>>(bsum);
    scan3_kernel<<<NB1, 256, 0, stream>>>(rowstart, bsum);
    hipMemsetAsync(deg, 0, NN * sizeof(int), stream);   // -> cursor
    scatter_kernel<<<(ET + 255) / 256, 256, 0, stream>>>(esrc, edst, rowstart, deg, csr_src);

    // ---- layer 1 ----
    transform_kernel<64, 128, 1, 2, 2, 64, false><<<(NN + 63) / 64, 256, 0, stream>>>(
        x, Wl1, bl1, Wr1, br1, xl1h, xr1h, NN);
    gat1_kernel<<<(NN + 3) / 4, 256, 0, stream>>>(
        rowstart, csr_src, xl1h, xr1h, att1, bias1, h1h);

    // ---- layer 2 ----
    transform_kernel<128, 32, 4, 2, 2, 64, true><<<(NN + 63) / 64, 256, 0, stream>>>(
        h1h, Wl2, bl2, Wr2, br2, xl2h, xr2h, NN);
    gat2_kernel<<<(NN + 7) / 8, 256, 0, stream>>>(
        rowstart, csr_src, xl2h, xr2h, att2, h2);

    // ---- pool + head ----
    pool_kernel<<<(NN + 255) / 256, 256, 0, stream>>>(h2, bias2, batch, pool, cnt);
    head_kernel<<<NG, 64, 0, stream>>>(pool, cnt, Wh1, bh1, Wh2, bh2, (float*)d_out);
}

// Round 15
// 337.769 us; speedup vs baseline: 1.3041x; 1.0014x over previous
//
#include <hip/hip_runtime.h>
#include <hip/hip_fp16.h>
#include <math.h>

#define NN 100000
#define NE 800000
#define ET (NN + NE)   /* 900000 edges incl self-loops */
#define GIN 64
#define CH 32
#define NH 4
#define NG 256
#define SLOPE 0.2f
#define LOG2E 1.44269504088896340736f
#define NB1 ((NN + 255) / 256)   /* 391 scan blocks */

typedef _Float16 f16x2 __attribute__((ext_vector_type(2)));

__device__ __forceinline__ void unpack8(float4 raw, float* x) {
    const __half2* hp = (const __half2*)&raw;
    #pragma unroll
    for (int j = 0; j < 4; ++j) {
        float2 f = __half22float2(hp[j]);
        x[2 * j] = f.x; x[2 * j + 1] = f.y;
    }
}
__device__ __forceinline__ void unpack4(float2 raw, float* x) {
    const __half2* hp = (const __half2*)&raw;
    #pragma unroll
    for (int j = 0; j < 2; ++j) {
        float2 f = __half22float2(hp[j]);
        x[2 * j] = f.x; x[2 * j + 1] = f.y;
    }
}

// ---- node transform: XLh = fp16(X@Wl+bl), XRh = fp16(X@Wr+br) ----
template<int K, int M, int TPC, int CPT, int NSUB, int NPB, bool INH>
__global__ __launch_bounds__(256, 2)
void transform_kernel(const void* __restrict__ Xv,
                      const float* __restrict__ Wl, const float* __restrict__ bl,
                      const float* __restrict__ Wr, const float* __restrict__ br,
                      __half* __restrict__ XLh, __half* __restrict__ XRh, int n)
{
    constexpr int KR   = K / TPC;
    constexpr int NCG  = 2 * M / CPT;
    __shared__ float sX[NPB * K];
    const int t      = threadIdx.x;
    const int ks     = t % TPC;
    const int colgrp = (t / TPC) % NCG;
    const int sub    = t / (TPC * NCG);
    const int k0     = ks * KR;
    const bool isR   = colgrp >= (M / CPT);
    const int cw0    = (colgrp - (isR ? M / CPT : 0)) * CPT;
    const float* W   = isR ? Wr : Wl;
    __half* const outp = isR ? XRh : XLh;
    float wreg[KR][CPT];
    #pragma unroll
    for (int k = 0; k < KR; ++k)
        #pragma unroll
        for (int j = 0; j < CPT; ++j)
            wreg[k][j] = W[(size_t)(k0 + k) * M + cw0 + j];
    float bias[CPT];
    #pragma unroll
    for (int j = 0; j < CPT; ++j)
        bias[j] = (ks == 0) ? (isR ? br[cw0 + j] : bl[cw0 + j]) : 0.f;

    const int base   = blockIdx.x * NPB;
    const int nvalid = (n - base < NPB) ? (n - base) : NPB;

    if constexpr (INH) {
        const __half* X = (const __half*)Xv;
        constexpr int QTOT = NPB * K / 8;
        for (int q = t; q < QTOT; q += 256) {
            const int node = q / (K / 8);
            const int qq   = q % (K / 8);
            float4 raw = (node < nvalid)
                             ? *(const float4*)(X + (size_t)(base + node) * K + qq * 8)
                             : make_float4(0.f, 0.f, 0.f, 0.f);
            unpack8(raw, sX + node * K + qq * 8);
        }
    } else {
        const float* X = (const float*)Xv;
        constexpr int QTOT = NPB * K / 4;
        for (int q = t; q < QTOT; q += 256) {
            const int node = q / (K / 4);
            const int qq   = q % (K / 4);
            float4 v = (node < nvalid)
                           ? *(const float4*)(X + (size_t)(base + node) * K + qq * 4)
                           : make_float4(0.f, 0.f, 0.f, 0.f);
            *(float4*)(sX + node * K + qq * 4) = v;
        }
    }
    __syncthreads();

    for (int nn = sub; nn < nvalid; nn += NSUB) {
        float acc[CPT];
        #pragma unroll
        for (int j = 0; j < CPT; ++j) acc[j] = bias[j];
        const float* xp = sX + nn * K + k0;
        #pragma unroll
        for (int kq = 0; kq < KR / 4; ++kq) {
            const float4 a = *(const float4*)(xp + kq * 4);
            #pragma unroll
            for (int j = 0; j < CPT; ++j) {
                acc[j] = fmaf(a.x, wreg[kq * 4 + 0][j], acc[j]);
                acc[j] = fmaf(a.y, wreg[kq * 4 + 1][j], acc[j]);
                acc[j] = fmaf(a.z, wreg[kq * 4 + 2][j], acc[j]);
                acc[j] = fmaf(a.w, wreg[kq * 4 + 3][j], acc[j]);
            }
        }
        if (TPC > 1) {
            #pragma unroll
            for (int off = 1; off < TPC; off <<= 1)
                #pragma unroll
                for (int j = 0; j < CPT; ++j)
                    acc[j] += __shfl_xor(acc[j], off);
        }
        if (ks == 0) {
            *(__half2*)(outp + (size_t)(base + nn) * M + cw0) =
                __float22half2_rn(make_float2(acc[0], acc[1]));
        }
    }
}

// ---- CSR build: histogram of dst ----
__global__ void hist_kernel(const int* __restrict__ edst, int* __restrict__ deg)
{
    int e = blockIdx.x * 256 + threadIdx.x;
    if (e >= ET) return;
    int d = (e < NE) ? edst[e] : (e - NE);
    atomicAdd(deg + d, 1);
}

// ---- 3-kernel exclusive scan ----
__global__ void scan1_kernel(const int* __restrict__ deg, int* __restrict__ rowstart,
                             int* __restrict__ bsum)
{
    __shared__ int lds[256];
    int t = threadIdx.x, idx = blockIdx.x * 256 + t;
    int v = (idx < NN) ? deg[idx] : 0;
    lds[t] = v;
    __syncthreads();
    #pragma unroll
    for (int off = 1; off < 256; off <<= 1) {
        int add = (t >= off) ? lds[t - off] : 0;
        __syncthreads();
        lds[t] += add;
        __syncthreads();
    }
    if (idx < NN) rowstart[idx + 1] = lds[t];
    if (t == 255) bsum[blockIdx.x] = lds[255];
}

__global__ void scan2_kernel(int* __restrict__ bsum)
{
    __shared__ int lds[512];
    int t = threadIdx.x;
    int v = (t < NB1) ? bsum[t] : 0;
    lds[t] = v;
    __syncthreads();
    #pragma unroll
    for (int off = 1; off < 512; off <<= 1) {
        int add = (t >= off) ? lds[t - off] : 0;
        __syncthreads();
        lds[t] += add;
        __syncthreads();
    }
    if (t < NB1) bsum[t] = lds[t] - v;
}

__global__ void scan3_kernel(int* __restrict__ rowstart, const int* __restrict__ bsum)
{
    int idx = blockIdx.x * 256 + threadIdx.x;
    if (idx == 0) rowstart[0] = 0;
    if (idx < NN) rowstart[idx + 1] += bsum[blockIdx.x];
}

// ---- CSR scatter ----
__global__ void scatter_kernel(const int* __restrict__ esrc, const int* __restrict__ edst,
                               const int* __restrict__ rowstart,
                               int* __restrict__ cursor, int* __restrict__ csr_src)
{
    int e = blockIdx.x * 256 + threadIdx.x;
    if (e >= ET) return;
    int s, d;
    if (e < NE) { s = esrc[e]; d = edst[e]; } else { s = e - NE; d = s; }
    int pos = rowstart[d] + atomicAdd(cursor + d, 1);
    csr_src[pos] = s;
}

// ---- layer 1 fused GATv2 (H=4, C=32): wave/node, 4 edge-slots.
// Logit in packed fp16 (v_pk_add/mul/max_f16 via f16x2 vector ops) feeding
// v_dot2_f32_f16 (f32 accumulate); defer-max rescale (THR=8 log2-units;
// first iteration rebases naturally via exp2(-inf)=0). ----
__global__ void gat1_kernel(const int* __restrict__ rowstart, const int* __restrict__ csr_src,
                            const __half* __restrict__ XLh, const __half* __restrict__ XRh,
                            const float* __restrict__ att, const float* __restrict__ bias,
                            __half* __restrict__ H1h)
{
    const int node = blockIdx.x * 4 + (threadIdx.x >> 6);
    if (node >= NN) return;
    const int lane = threadIdx.x & 63;
    const int slot = lane >> 4;
    const int q    = lane & 15;
    const int c0   = q * 8;

    float4 xr_raw = *(const float4*)(XRh + (size_t)node * 128 + c0);
    const f16x2* xrh = (const f16x2*)&xr_raw;
    f16x2 ath[4];
    {
        const float4 a0 = *(const float4*)(att + c0);
        const float4 a1 = *(const float4*)(att + c0 + 4);
        ath[0] = (f16x2){(_Float16)(a0.x * LOG2E), (_Float16)(a0.y * LOG2E)};
        ath[1] = (f16x2){(_Float16)(a0.z * LOG2E), (_Float16)(a0.w * LOG2E)};
        ath[2] = (f16x2){(_Float16)(a1.x * LOG2E), (_Float16)(a1.y * LOG2E)};
        ath[3] = (f16x2){(_Float16)(a1.z * LOG2E), (_Float16)(a1.w * LOG2E)};
    }
    const f16x2 s2 = {(_Float16)SLOPE, (_Float16)SLOPE};
    const int beg = rowstart[node], end = rowstart[node + 1];
    float m = -INFINITY, ssum = 0.f;
    float acc[8] = {0.f, 0.f, 0.f, 0.f, 0.f, 0.f, 0.f, 0.f};

    for (int i = beg; i < end; i += 4) {
        const int idx    = i + slot;
        const bool valid = idx < end;
        const int s = valid ? csr_src[idx] : 0;
        float4 xl_raw = *(const float4*)(XLh + (size_t)s * 128 + c0);
        const f16x2* xlh = (const f16x2*)&xl_raw;
        float p = 0.f;
        #pragma unroll
        for (int j = 0; j < 4; ++j) {
            f16x2 v  = xlh[j] + xrh[j];                       // v_pk_add_f16
            f16x2 lv = __builtin_elementwise_max(v, s2 * v);  // leaky_relu (packed)
            p = __builtin_amdgcn_fdot2(lv, ath[j], p, false); // v_dot2_f32_f16
        }
        p += __shfl_xor(p, 1);
        p += __shfl_xor(p, 2);                // per-head logit (log2 units)
        if (!valid) p = -INFINITY;
        float pm = fmaxf(p, __shfl_xor(p, 16));
        pm = fmaxf(pm, __shfl_xor(pm, 32));   // max over 4 slots
        if (__any(pm > m + 8.f)) {            // rare (always on first iter)
            const float mn = fmaxf(m, pm);
            const float sc = exp2f(m - mn);   // exp2(-inf)=0 zeroes nothing
            ssum *= sc;
            #pragma unroll
            for (int j = 0; j < 8; ++j) acc[j] *= sc;
            m = mn;
        }
        const float e = exp2f(p - m);         // <= 2^8; 0 for invalid slots
        ssum += e;
        float xlf[8];
        unpack8(xl_raw, xlf);
        #pragma unroll
        for (int j = 0; j < 8; ++j)
            acc[j] = fmaf(e, xlf[j], acc[j]);
    }
    // merge slots
    ssum += __shfl_xor(ssum, 16);
    ssum += __shfl_xor(ssum, 32);
    #pragma unroll
    for (int j = 0; j < 8; ++j) {
        acc[j] += __shfl_xor(acc[j], 16);
        acc[j] += __shfl_xor(acc[j], 32);
    }
    if (slot == 0) {
        const float inv = 1.f / (ssum + 1e-16f);
        const float4 b0 = *(const float4*)(bias + c0);
        const float4 b1 = *(const float4*)(bias + c0 + 4);
        const float bb[8] = {b0.x, b0.y, b0.z, b0.w, b1.x, b1.y, b1.z, b1.w};
        __half2 outh[4];
        #pragma unroll
        for (int j = 0; j < 4; ++j) {
            float o0 = acc[2 * j] * inv + bb[2 * j];
            float o1 = acc[2 * j + 1] * inv + bb[2 * j + 1];
            o0 = o0 > 0.f ? o0 : expm1f(o0);  // CELU(alpha=1)
            o1 = o1 > 0.f ? o1 : expm1f(o1);
            outh[j] = __float22half2_rn(make_float2(o0, o1));
        }
        *(float4*)(H1h + (size_t)node * 128 + c0) = *(const float4*)outh;
    }
}

// ---- layer 2 fused GATv2 (H=1, C=32): 32 lanes/node, 4 edge-slots; same tricks.
// (__any spans 2 nodes per wave: a spurious rescale is harmless — mn=fmax(m,pm).)
__global__ void gat2_kernel(const int* __restrict__ rowstart, const int* __restrict__ csr_src,
                            const __half* __restrict__ XLh, const __half* __restrict__ XRh,
                            const float* __restrict__ att,
                            float* __restrict__ H2)
{
    const int node = blockIdx.x * 8 + (threadIdx.x >> 5);
    if (node >= NN) return;
    const int l2   = threadIdx.x & 31;
    const int slot = l2 >> 3;
    const int q    = l2 & 7;
    const int c0   = q * 4;

    float2 xr_raw = *(const float2*)(XRh + (size_t)node * 32 + c0);
    const f16x2* xrh = (const f16x2*)&xr_raw;
    f16x2 ath[2];
    {
        const float4 a = *(const float4*)(att + c0);
        ath[0] = (f16x2){(_Float16)(a.x * LOG2E), (_Float16)(a.y * LOG2E)};
        ath[1] = (f16x2){(_Float16)(a.z * LOG2E), (_Float16)(a.w * LOG2E)};
    }
    const f16x2 s2 = {(_Float16)SLOPE, (_Float16)SLOPE};
    const int beg = rowstart[node], end = rowstart[node + 1];
    float m = -INFINITY, ssum = 0.f;
    float acc[4] = {0.f, 0.f, 0.f, 0.f};

    for (int i = beg; i < end; i += 4) {
        const int idx    = i + slot;
        const bool valid = idx < end;
        const int s = valid ? csr_src[idx] : 0;
        float2 xl_raw = *(const float2*)(XLh + (size_t)s * 32 + c0);
        const f16x2* xlh = (const f16x2*)&xl_raw;
        float p = 0.f;
        #pragma unroll
        for (int j = 0; j < 2; ++j) {
            f16x2 v  = xlh[j] + xrh[j];
            f16x2 lv = __builtin_elementwise_max(v, s2 * v);
            p = __builtin_amdgcn_fdot2(lv, ath[j], p, false);
        }
        p += __shfl_xor(p, 1);
        p += __shfl_xor(p, 2);
        p += __shfl_xor(p, 4);                // full 32-ch logit
        if (!valid) p = -INFINITY;
        float pm = fmaxf(p, __shfl_xor(p, 8));
        pm = fmaxf(pm, __shfl_xor(pm, 16));
        if (__any(pm > m + 8.f)) {
            const float mn = fmaxf(m, pm);
            const float sc = exp2f(m - mn);
            ssum *= sc;
            #pragma unroll
            for (int j = 0; j < 4; ++j) acc[j] *= sc;
            m = mn;
        }
        const float e = exp2f(p - m);
        ssum += e;
        float xlf[4];
        unpack4(xl_raw, xlf);
        #pragma unroll
        for (int j = 0; j < 4; ++j)
            acc[j] = fmaf(e, xlf[j], acc[j]);
    }
    ssum += __shfl_xor(ssum, 8);
    ssum += __shfl_xor(ssum, 16);
    #pragma unroll
    for (int j = 0; j < 4; ++j) {
        acc[j] += __shfl_xor(acc[j], 8);
        acc[j] += __shfl_xor(acc[j], 16);
    }
    if (slot == 0) {
        const float inv = 1.f / (ssum + 1e-16f);
        float4 o;
        o.x = acc[0] * inv; o.y = acc[1] * inv;
        o.z = acc[2] * inv; o.w = acc[3] * inv;
        *(float4*)(H2 + (size_t)node * 32 + c0) = o;
    }
}

// ---- mean-pool (batch sorted: run-length accumulate, then atomic flush) ----
__global__ void pool_kernel(const float* __restrict__ h2, const float* __restrict__ bias2,
                            const int* __restrict__ batch,
                            float* __restrict__ pool, float* __restrict__ cnt)
{
    const int c    = threadIdx.x & 31;
    const int slot = threadIdx.x >> 5;     // 0..7
    const int base = blockIdx.x * 256;
    const float b = bias2[c];
    float acc = 0.f, cacc = 0.f;
    int curg = -1;
    for (int i = slot; i < 256; i += 8) {
        int node = base + i;
        if (node >= NN) break;
        int g = batch[node];
        if (g != curg) {
            if (curg >= 0) {
                atomicAdd(pool + (size_t)curg * 32 + c, acc);
                if (c == 0) atomicAdd(cnt + curg, cacc);
            }
            acc = 0.f; cacc = 0.f; curg = g;
        }
        acc += h2[(size_t)node * 32 + c] + b;
        cacc += 1.f;
    }
    if (curg >= 0) {
        atomicAdd(pool + (size_t)curg * 32 + c, acc);
        if (c == 0) atomicAdd(cnt + curg, cacc);
    }
}

// ---- per-graph head MLP ----
__global__ void head_kernel(const float* __restrict__ pool, const float* __restrict__ cnt,
                            const float* __restrict__ Wh1, const float* __restrict__ bh1,
                            const float* __restrict__ Wh2, const float* __restrict__ bh2,
                            float* __restrict__ out)
{
    int g = blockIdx.x;
    int c = threadIdx.x;      // 0..63
    float partial = 0.f;
    if (c < 32) {
        float invc = 1.f / fmaxf(cnt[g], 1.f);
        float acc = bh1[c];
        #pragma unroll
        for (int k = 0; k < 32; ++k)
            acc = fmaf(pool[g * 32 + k] * invc, Wh1[k * 32 + c], acc);
        float z = fmaxf(acc, 0.f);
        partial = z * Wh2[c];
    }
    #pragma unroll
    for (int off = 32; off >= 1; off >>= 1)
        partial += __shfl_down(partial, off);
    if (c == 0) out[g] = partial + bh2[0];
}

extern "C" void kernel_launch(void* const* d_in, const int* in_sizes, int n_in,
                              void* d_out, int out_size, void* d_ws, size_t ws_size,
                              hipStream_t stream)
{
    const float* x     = (const float*)d_in[0];
    const int*   ei    = (const int*)d_in[1];
    const int*   batch = (const int*)d_in[2];
    const float* Wl1   = (const float*)d_in[3];
    const float* bl1   = (const float*)d_in[4];
    const float* Wr1   = (const float*)d_in[5];
    const float* br1   = (const float*)d_in[6];
    const float* att1  = (const float*)d_in[7];
    const float* bias1 = (const float*)d_in[8];
    const float* Wl2   = (const float*)d_in[9];
    const float* bl2   = (const float*)d_in[10];
    const float* Wr2   = (const float*)d_in[11];
    const float* br2   = (const float*)d_in[12];
    const float* att2  = (const float*)d_in[13];
    const float* bias2 = (const float*)d_in[14];
    const float* Wh1   = (const float*)d_in[15];
    const float* bh1   = (const float*)d_in[16];
    const float* Wh2   = (const float*)d_in[17];
    const float* bh2   = (const float*)d_in[18];
    const int* esrc = ei;
    const int* edst = ei + NE;

    // ---- workspace layout (bytes) ----
    char* wsb = (char*)d_ws;
    __half* xl1h = (__half*)wsb;                               // NN*128*2
    __half* xr1h = (__half*)(wsb + (size_t)NN * 128 * 2);      // NN*128*2
    __half* h1h  = xr1h;                                       // alias (per-row RAW in-wave)
    char* p2 = wsb + (size_t)NN * 128 * 4;
    __half* xl2h = (__half*)p2;                                // NN*32*2
    __half* xr2h = (__half*)(p2 + (size_t)NN * 32 * 2);        // NN*32*2
    float*  h2   = (float*)(p2 + (size_t)NN * 32 * 4);         // NN*32*4
    float*  pool = (float*)(p2 + (size_t)NN * 32 * 8);
    float*  cnt  = pool + (size_t)NG * 32;                     // NG
    int* ib       = (int*)(cnt + NG);
    int* deg      = ib;                                        // NN (reused as cursor)
    int* rowstart = ib + NN;                                   // NN+1
    int* bsum     = ib + 2 * NN + 1;                           // 512
    int* csr_src  = ib + 2 * NN + 1 + 512;                     // ET

    // ---- CSR build ----
    hipMemsetAsync(deg, 0, NN * sizeof(int), stream);
    hipMemsetAsync(pool, 0, (size_t)(NG * 33) * sizeof(float), stream);
    hist_kernel<<<(ET + 255) / 256, 256, 0, stream>>>(edst, deg);
    scan1_kernel<<<NB1, 256, 0, stream>>>(deg, rowstart, bsum);
    scan2_kernel<<<1, 512, 0, stream>>>(bsum);
    scan3_kernel<<<NB1, 256, 0, stream>>>(rowstart, bsum);
    hipMemsetAsync(deg, 0, NN * sizeof(int), stream);   // -> cursor
    scatter_kernel<<<(ET + 255) / 256, 256, 0, stream>>>(esrc, edst, rowstart, deg, csr_src);

    // ---- layer 1 ----
    transform_kernel<64, 128, 1, 2, 2, 64, false><<<(NN + 63) / 64, 256, 0, stream>>>(
        x, Wl1, bl1, Wr1, br1, xl1h, xr1h, NN);
    gat1_kernel<<<(NN + 3) / 4, 256, 0, stream>>>(
        rowstart, csr_src, xl1h, xr1h, att1, bias1, h1h);

    // ---- layer 2 ----
    transform_kernel<128, 32, 4, 2, 2, 64, true><<<(NN + 63) / 64, 256, 0, stream>>>(
        h1h, Wl2, bl2, Wr2, br2, xl2h, xr2h, NN);
    gat2_kernel<<<(NN + 7) / 8, 256, 0, stream>>>(
        rowstart, csr_src, xl2h, xr2h, att2, h2);

    // ---- pool + head ----
    pool_kernel<<<(NN + 255) / 256, 256, 0, stream>>>(h2, bias2, batch, pool, cnt);
    head_kernel<<<NG, 64, 0, stream>>>(pool, cnt, Wh1, bh1, Wh2, bh2, (float*)d_out);
}

// Round 17
// 281.951 us; speedup vs baseline: 1.5623x; 1.1980x over previous
//
#include <hip/hip_runtime.h>
#include <hip/hip_fp16.h>
#include <math.h>

#define NN 100000
#define NE 800000
#define ET (NN + NE)   /* 900000 edges incl self-loops */
#define NG 256
#define SLOPE 0.2f
#define LOG2E 1.44269504088896340736f
#define NB1 ((NN + 255) / 256)   /* 391 scan blocks */
#define NRT 6250                 /* 100000/16 row tiles */

typedef _Float16 f16x2 __attribute__((ext_vector_type(2)));
typedef _Float16 f16x8 __attribute__((ext_vector_type(8)));
typedef float    f32x4 __attribute__((ext_vector_type(4)));

__device__ __forceinline__ void unpack8(float4 raw, float* x) {
    const __half2* hp = (const __half2*)&raw;
    #pragma unroll
    for (int j = 0; j < 4; ++j) {
        float2 f = __half22float2(hp[j]);
        x[2 * j] = f.x; x[2 * j + 1] = f.y;
    }
}
__device__ __forceinline__ void unpack4(float2 raw, float* x) {
    const __half2* hp = (const __half2*)&raw;
    #pragma unroll
    for (int j = 0; j < 2; ++j) {
        float2 f = __half22float2(hp[j]);
        x[2 * j] = f.x; x[2 * j + 1] = f.y;
    }
}

// ---- pack W (f32 [K][Mhalf] Wl|Wr) into MFMA B-fragment order, hi/lo fp16 ----
// frag addr = ((ct*KS+ks)*64 + lane)*8 + i  holds  W[k=ks*32+(l>>4)*8+i][col=ct*16+(l&15)]
template<int K, int MT, int MHALF>
__global__ void packW_kernel(const float* __restrict__ Wl, const float* __restrict__ Wr,
                             __half* __restrict__ hi, __half* __restrict__ lo)
{
    constexpr int KS  = K / 32;
    constexpr int TOT = (MT / 16) * KS * 64 * 8;
    for (int idx = blockIdx.x * 256 + threadIdx.x; idx < TOT; idx += gridDim.x * 256) {
        const int i   = idx & 7;
        const int l   = (idx >> 3) & 63;
        const int rem = idx >> 9;
        const int ks  = rem % KS;
        const int ct  = rem / KS;
        const int k   = ks * 32 + (l >> 4) * 8 + i;
        const int col = ct * 16 + (l & 15);
        const float w = (col < MHALF) ? Wl[(size_t)k * MHALF + col]
                                      : Wr[(size_t)k * MHALF + (col - MHALF)];
        const __half h = __float2half(w);
        hi[idx] = h;
        lo[idx] = __float2half(w - __half2float(h));
    }
}

// ---- transform 1 via MFMA: XL|XR (256 cols) = X(f32,K=64) @ [Wl|Wr] + bias ----
// one wave per 16-row tile; A: lane holds X[rt*16+(l&15)][ks*32+(l>>4)*8 ..+7]
__global__ __launch_bounds__(256, 4)
void t1_mfma_kernel(const float* __restrict__ X,
                    const __half* __restrict__ Whi, const __half* __restrict__ Wlo,
                    const float* __restrict__ bl, const float* __restrict__ br,
                    __half* __restrict__ XLh, __half* __restrict__ XRh)
{
    const int rt = blockIdx.x * 4 + (threadIdx.x >> 6);
    if (rt >= NRT) return;
    const int l = threadIdx.x & 63;
    const int row_a = rt * 16 + (l & 15);
    const int kbase = (l >> 4) * 8;

    f16x8 a[2];
    #pragma unroll
    for (int ks = 0; ks < 2; ++ks) {
        const float4 x0 = *(const float4*)(X + (size_t)row_a * 64 + ks * 32 + kbase);
        const float4 x1 = *(const float4*)(X + (size_t)row_a * 64 + ks * 32 + kbase + 4);
        a[ks][0] = (_Float16)x0.x; a[ks][1] = (_Float16)x0.y;
        a[ks][2] = (_Float16)x0.z; a[ks][3] = (_Float16)x0.w;
        a[ks][4] = (_Float16)x1.x; a[ks][5] = (_Float16)x1.y;
        a[ks][6] = (_Float16)x1.z; a[ks][7] = (_Float16)x1.w;
    }

    for (int ct = 0; ct < 16; ++ct) {
        f32x4 acc = {0.f, 0.f, 0.f, 0.f};
        #pragma unroll
        for (int ks = 0; ks < 2; ++ks) {
            const f16x8 bh = *(const f16x8*)(Whi + ((size_t)(ct * 2 + ks) * 64 + l) * 8);
            const f16x8 bL = *(const f16x8*)(Wlo + ((size_t)(ct * 2 + ks) * 64 + l) * 8);
            acc = __builtin_amdgcn_mfma_f32_16x16x32_f16(a[ks], bh, acc, 0, 0, 0);
            acc = __builtin_amdgcn_mfma_f32_16x16x32_f16(a[ks], bL, acc, 0, 0, 0);
        }
        const int col = ct * 16 + (l & 15);
        const float bias = (col < 128) ? bl[col] : br[col - 128];
        __half* const dst = (col < 128) ? XLh : XRh;
        const int dcol = col & 127;
        #pragma unroll
        for (int r = 0; r < 4; ++r) {
            const int row = rt * 16 + (l >> 4) * 4 + r;
            dst[(size_t)row * 128 + dcol] = __float2half(acc[r] + bias);
        }
    }
}

// ---- transform 2 via MFMA: XL2|XR2 (64 cols) = H1(fp16,K=128) @ [Wl2|Wr2] + bias ----
__global__ __launch_bounds__(256, 4)
void t2_mfma_kernel(const __half* __restrict__ H1h,
                    const __half* __restrict__ Whi, const __half* __restrict__ Wlo,
                    const float* __restrict__ bl, const float* __restrict__ br,
                    __half* __restrict__ XLh, __half* __restrict__ XRh)
{
    const int rt = blockIdx.x * 4 + (threadIdx.x >> 6);
    if (rt >= NRT) return;
    const int l = threadIdx.x & 63;
    const int row_a = rt * 16 + (l & 15);
    const int kbase = (l >> 4) * 8;

    f16x8 a[4];
    #pragma unroll
    for (int ks = 0; ks < 4; ++ks)
        a[ks] = *(const f16x8*)(H1h + (size_t)row_a * 128 + ks * 32 + kbase);

    for (int ct = 0; ct < 4; ++ct) {
        f32x4 acc = {0.f, 0.f, 0.f, 0.f};
        #pragma unroll
        for (int ks = 0; ks < 4; ++ks) {
            const f16x8 bh = *(const f16x8*)(Whi + ((size_t)(ct * 4 + ks) * 64 + l) * 8);
            const f16x8 bL = *(const f16x8*)(Wlo + ((size_t)(ct * 4 + ks) * 64 + l) * 8);
            acc = __builtin_amdgcn_mfma_f32_16x16x32_f16(a[ks], bh, acc, 0, 0, 0);
            acc = __builtin_amdgcn_mfma_f32_16x16x32_f16(a[ks], bL, acc, 0, 0, 0);
        }
        const int col = ct * 16 + (l & 15);
        const float bias = (col < 32) ? bl[col] : br[col - 32];
        __half* const dst = (col < 32) ? XLh : XRh;
        const int dcol = col & 31;
        #pragma unroll
        for (int r = 0; r < 4; ++r) {
            const int row = rt * 16 + (l >> 4) * 4 + r;
            dst[(size_t)row * 32 + dcol] = __float2half(acc[r] + bias);
        }
    }
}

// ---- CSR build: histogram of dst ----
__global__ void hist_kernel(const int* __restrict__ edst, int* __restrict__ deg)
{
    int e = blockIdx.x * 256 + threadIdx.x;
    if (e >= ET) return;
    int d = (e < NE) ? edst[e] : (e - NE);
    atomicAdd(deg + d, 1);
}

// ---- 3-kernel exclusive scan ----
__global__ void scan1_kernel(const int* __restrict__ deg, int* __restrict__ rowstart,
                             int* __restrict__ bsum)
{
    __shared__ int lds[256];
    int t = threadIdx.x, idx = blockIdx.x * 256 + t;
    int v = (idx < NN) ? deg[idx] : 0;
    lds[t] = v;
    __syncthreads();
    #pragma unroll
    for (int off = 1; off < 256; off <<= 1) {
        int add = (t >= off) ? lds[t - off] : 0;
        __syncthreads();
        lds[t] += add;
        __syncthreads();
    }
    if (idx < NN) rowstart[idx + 1] = lds[t];
    if (t == 255) bsum[blockIdx.x] = lds[255];
}

__global__ void scan2_kernel(int* __restrict__ bsum)
{
    __shared__ int lds[512];
    int t = threadIdx.x;
    int v = (t < NB1) ? bsum[t] : 0;
    lds[t] = v;
    __syncthreads();
    #pragma unroll
    for (int off = 1; off < 512; off <<= 1) {
        int add = (t >= off) ? lds[t - off] : 0;
        __syncthreads();
        lds[t] += add;
        __syncthreads();
    }
    if (t < NB1) bsum[t] = lds[t] - v;
}

__global__ void scan3_kernel(int* __restrict__ rowstart, const int* __restrict__ bsum)
{
    int idx = blockIdx.x * 256 + threadIdx.x;
    if (idx == 0) rowstart[0] = 0;
    if (idx < NN) rowstart[idx + 1] += bsum[blockIdx.x];
}

// ---- CSR scatter ----
__global__ void scatter_kernel(const int* __restrict__ esrc, const int* __restrict__ edst,
                               const int* __restrict__ rowstart,
                               int* __restrict__ cursor, int* __restrict__ csr_src)
{
    int e = blockIdx.x * 256 + threadIdx.x;
    if (e >= ET) return;
    int s, d;
    if (e < NE) { s = esrc[e]; d = edst[e]; } else { s = e - NE; d = s; }
    int pos = rowstart[d] + atomicAdd(cursor + d, 1);
    csr_src[pos] = s;
}

// ---- layer 1 fused GATv2 (H=4, C=32): wave/node, 4 edge-slots (R15 state) ----
__global__ void gat1_kernel(const int* __restrict__ rowstart, const int* __restrict__ csr_src,
                            const __half* __restrict__ XLh, const __half* __restrict__ XRh,
                            const float* __restrict__ att, const float* __restrict__ bias,
                            __half* __restrict__ H1h)
{
    const int node = blockIdx.x * 4 + (threadIdx.x >> 6);
    if (node >= NN) return;
    const int lane = threadIdx.x & 63;
    const int slot = lane >> 4;
    const int q    = lane & 15;
    const int c0   = q * 8;

    float4 xr_raw = *(const float4*)(XRh + (size_t)node * 128 + c0);
    const f16x2* xrh = (const f16x2*)&xr_raw;
    f16x2 ath[4];
    {
        const float4 a0 = *(const float4*)(att + c0);
        const float4 a1 = *(const float4*)(att + c0 + 4);
        ath[0] = (f16x2){(_Float16)(a0.x * LOG2E), (_Float16)(a0.y * LOG2E)};
        ath[1] = (f16x2){(_Float16)(a0.z * LOG2E), (_Float16)(a0.w * LOG2E)};
        ath[2] = (f16x2){(_Float16)(a1.x * LOG2E), (_Float16)(a1.y * LOG2E)};
        ath[3] = (f16x2){(_Float16)(a1.z * LOG2E), (_Float16)(a1.w * LOG2E)};
    }
    const f16x2 s2 = {(_Float16)SLOPE, (_Float16)SLOPE};
    const int beg = rowstart[node], end = rowstart[node + 1];
    float m = -INFINITY, ssum = 0.f;
    float acc[8] = {0.f, 0.f, 0.f, 0.f, 0.f, 0.f, 0.f, 0.f};

    for (int i = beg; i < end; i += 4) {
        const int idx    = i + slot;
        const bool valid = idx < end;
        const int s = valid ? csr_src[idx] : 0;
        float4 xl_raw = *(const float4*)(XLh + (size_t)s * 128 + c0);
        const f16x2* xlh = (const f16x2*)&xl_raw;
        float p = 0.f;
        #pragma unroll
        for (int j = 0; j < 4; ++j) {
            f16x2 v  = xlh[j] + xrh[j];
            f16x2 lv = __builtin_elementwise_max(v, s2 * v);
            p = __builtin_amdgcn_fdot2(lv, ath[j], p, false);
        }
        p += __shfl_xor(p, 1);
        p += __shfl_xor(p, 2);
        if (!valid) p = -INFINITY;
        float pm = fmaxf(p, __shfl_xor(p, 16));
        pm = fmaxf(pm, __shfl_xor(pm, 32));
        if (__any(pm > m + 8.f)) {
            const float mn = fmaxf(m, pm);
            const float sc = exp2f(m - mn);
            ssum *= sc;
            #pragma unroll
            for (int j = 0; j < 8; ++j) acc[j] *= sc;
            m = mn;
        }
        const float e = exp2f(p - m);
        ssum += e;
        float xlf[8];
        unpack8(xl_raw, xlf);
        #pragma unroll
        for (int j = 0; j < 8; ++j)
            acc[j] = fmaf(e, xlf[j], acc[j]);
    }
    ssum += __shfl_xor(ssum, 16);
    ssum += __shfl_xor(ssum, 32);
    #pragma unroll
    for (int j = 0; j < 8; ++j) {
        acc[j] += __shfl_xor(acc[j], 16);
        acc[j] += __shfl_xor(acc[j], 32);
    }
    if (slot == 0) {
        const float inv = 1.f / (ssum + 1e-16f);
        const float4 b0 = *(const float4*)(bias + c0);
        const float4 b1 = *(const float4*)(bias + c0 + 4);
        const float bb[8] = {b0.x, b0.y, b0.z, b0.w, b1.x, b1.y, b1.z, b1.w};
        __half2 outh[4];
        #pragma unroll
        for (int j = 0; j < 4; ++j) {
            float o0 = acc[2 * j] * inv + bb[2 * j];
            float o1 = acc[2 * j + 1] * inv + bb[2 * j + 1];
            o0 = o0 > 0.f ? o0 : expm1f(o0);
            o1 = o1 > 0.f ? o1 : expm1f(o1);
            outh[j] = __float22half2_rn(make_float2(o0, o1));
        }
        *(float4*)(H1h + (size_t)node * 128 + c0) = *(const float4*)outh;
    }
}

// ---- layer 2 fused GATv2 (H=1, C=32): 32 lanes/node, 4 edge-slots (R15 state) ----
__global__ void gat2_kernel(const int* __restrict__ rowstart, const int* __restrict__ csr_src,
                            const __half* __restrict__ XLh, const __half* __restrict__ XRh,
                            const float* __restrict__ att,
                            float* __restrict__ H2)
{
    const int node = blockIdx.x * 8 + (threadIdx.x >> 5);
    if (node >= NN) return;
    const int l2   = threadIdx.x & 31;
    const int slot = l2 >> 3;
    const int q    = l2 & 7;
    const int c0   = q * 4;

    float2 xr_raw = *(const float2*)(XRh + (size_t)node * 32 + c0);
    const f16x2* xrh = (const f16x2*)&xr_raw;
    f16x2 ath[2];
    {
        const float4 a = *(const float4*)(att + c0);
        ath[0] = (f16x2){(_Float16)(a.x * LOG2E), (_Float16)(a.y * LOG2E)};
        ath[1] = (f16x2){(_Float16)(a.z * LOG2E), (_Float16)(a.w * LOG2E)};
    }
    const f16x2 s2 = {(_Float16)SLOPE, (_Float16)SLOPE};
    const int beg = rowstart[node], end = rowstart[node + 1];
    float m = -INFINITY, ssum = 0.f;
    float acc[4] = {0.f, 0.f, 0.f, 0.f};

    for (int i = beg; i < end; i += 4) {
        const int idx    = i + slot;
        const bool valid = idx < end;
        const int s = valid ? csr_src[idx] : 0;
        float2 xl_raw = *(const float2*)(XLh + (size_t)s * 32 + c0);
        const f16x2* xlh = (const f16x2*)&xl_raw;
        float p = 0.f;
        #pragma unroll
        for (int j = 0; j < 2; ++j) {
            f16x2 v  = xlh[j] + xrh[j];
            f16x2 lv = __builtin_elementwise_max(v, s2 * v);
            p = __builtin_amdgcn_fdot2(lv, ath[j], p, false);
        }
        p += __shfl_xor(p, 1);
        p += __shfl_xor(p, 2);
        p += __shfl_xor(p, 4);
        if (!valid) p = -INFINITY;
        float pm = fmaxf(p, __shfl_xor(p, 8));
        pm = fmaxf(pm, __shfl_xor(pm, 16));
        if (__any(pm > m + 8.f)) {
            const float mn = fmaxf(m, pm);
            const float sc = exp2f(m - mn);
            ssum *= sc;
            #pragma unroll
            for (int j = 0; j < 4; ++j) acc[j] *= sc;
            m = mn;
        }
        const float e = exp2f(p - m);
        ssum += e;
        float xlf[4];
        unpack4(xl_raw, xlf);
        #pragma unroll
        for (int j = 0; j < 4; ++j)
            acc[j] = fmaf(e, xlf[j], acc[j]);
    }
    ssum += __shfl_xor(ssum, 8);
    ssum += __shfl_xor(ssum, 16);
    #pragma unroll
    for (int j = 0; j < 4; ++j) {
        acc[j] += __shfl_xor(acc[j], 8);
        acc[j] += __shfl_xor(acc[j], 16);
    }
    if (slot == 0) {
        const float inv = 1.f / (ssum + 1e-16f);
        float4 o;
        o.x = acc[0] * inv; o.y = acc[1] * inv;
        o.z = acc[2] * inv; o.w = acc[3] * inv;
        *(float4*)(H2 + (size_t)node * 32 + c0) = o;
    }
}

// ---- mean-pool (batch sorted: run-length accumulate, then atomic flush) ----
__global__ void pool_kernel(const float* __restrict__ h2, const float* __restrict__ bias2,
                            const int* __restrict__ batch,
                            float* __restrict__ pool, float* __restrict__ cnt)
{
    const int c    = threadIdx.x & 31;
    const int slot = threadIdx.x >> 5;     // 0..7
    const int base = blockIdx.x * 256;
    const float b = bias2[c];
    float acc = 0.f, cacc = 0.f;
    int curg = -1;
    for (int i = slot; i < 256; i += 8) {
        int node = base + i;
        if (node >= NN) break;
        int g = batch[node];
        if (g != curg) {
            if (curg >= 0) {
                atomicAdd(pool + (size_t)curg * 32 + c, acc);
                if (c == 0) atomicAdd(cnt + curg, cacc);
            }
            acc = 0.f; cacc = 0.f; curg = g;
        }
        acc += h2[(size_t)node * 32 + c] + b;
        cacc += 1.f;
    }
    if (curg >= 0) {
        atomicAdd(pool + (size_t)curg * 32 + c, acc);
        if (c == 0) atomicAdd(cnt + curg, cacc);
    }
}

// ---- per-graph head MLP ----
__global__ void head_kernel(const float* __restrict__ pool, const float* __restrict__ cnt,
                            const float* __restrict__ Wh1, const float* __restrict__ bh1,
                            const float* __restrict__ Wh2, const float* __restrict__ bh2,
                            float* __restrict__ out)
{
    int g = blockIdx.x;
    int c = threadIdx.x;      // 0..63
    float partial = 0.f;
    if (c < 32) {
        float invc = 1.f / fmaxf(cnt[g], 1.f);
        float acc = bh1[c];
        #pragma unroll
        for (int k = 0; k < 32; ++k)
            acc = fmaf(pool[g * 32 + k] * invc, Wh1[k * 32 + c], acc);
        float z = fmaxf(acc, 0.f);
        partial = z * Wh2[c];
    }
    #pragma unroll
    for (int off = 32; off >= 1; off >>= 1)
        partial += __shfl_down(partial, off);
    if (c == 0) out[g] = partial + bh2[0];
}

extern "C" void kernel_launch(void* const* d_in, const int* in_sizes, int n_in,
                              void* d_out, int out_size, void* d_ws, size_t ws_size,
                              hipStream_t stream)
{
    const float* x     = (const float*)d_in[0];
    const int*   ei    = (const int*)d_in[1];
    const int*   batch = (const int*)d_in[2];
    const float* Wl1   = (const float*)d_in[3];
    const float* bl1   = (const float*)d_in[4];
    const float* Wr1   = (const float*)d_in[5];
    const float* br1   = (const float*)d_in[6];
    const float* att1  = (const float*)d_in[7];
    const float* bias1 = (const float*)d_in[8];
    const float* Wl2   = (const float*)d_in[9];
    const float* bl2   = (const float*)d_in[10];
    const float* Wr2   = (const float*)d_in[11];
    const float* br2   = (const float*)d_in[12];
    const float* att2  = (const float*)d_in[13];
    const float* bias2 = (const float*)d_in[14];
    const float* Wh1   = (const float*)d_in[15];
    const float* bh1   = (const float*)d_in[16];
    const float* Wh2   = (const float*)d_in[17];
    const float* bh2   = (const float*)d_in[18];
    const int* esrc = ei;
    const int* edst = ei + NE;

    // ---- workspace layout (bytes) ----
    char* wsb = (char*)d_ws;
    __half* xl1h = (__half*)wsb;                               // NN*128*2
    __half* xr1h = (__half*)(wsb + (size_t)NN * 128 * 2);      // NN*128*2
    __half* h1h  = xr1h;                                       // alias (per-row RAW in-wave)
    char* p2 = wsb + (size_t)NN * 128 * 4;
    __half* xl2h = (__half*)p2;                                // NN*32*2
    __half* xr2h = (__half*)(p2 + (size_t)NN * 32 * 2);        // NN*32*2
    float*  h2   = (float*)(p2 + (size_t)NN * 32 * 4);         // NN*32*4
    float*  pool = (float*)(p2 + (size_t)NN * 32 * 8);
    float*  cnt  = pool + (size_t)NG * 32;                     // NG
    int* ib       = (int*)(cnt + NG);
    int* deg      = ib;                                        // NN (reused as cursor)
    int* rowstart = ib + NN;                                   // NN+1
    int* bsum     = ib + 2 * NN + 1;                           // 512
    int* csr_src  = ib + 2 * NN + 1 + 512;                     // ET
    __half* whi1  = (__half*)(csr_src + ET);                   // 16*2*64*8 = 16384
    __half* wlo1  = whi1 + 16384;
    __half* whi2  = wlo1 + 16384;                              // 4*4*64*8 = 8192
    __half* wlo2  = whi2 + 8192;

    // ---- CSR build + W packing ----
    hipMemsetAsync(deg, 0, NN * sizeof(int), stream);
    hipMemsetAsync(pool, 0, (size_t)(NG * 33) * sizeof(float), stream);
    packW_kernel<64, 256, 128><<<64, 256, 0, stream>>>(Wl1, Wr1, whi1, wlo1);
    packW_kernel<128, 64, 32><<<32, 256, 0, stream>>>(Wl2, Wr2, whi2, wlo2);
    hist_kernel<<<(ET + 255) / 256, 256, 0, stream>>>(edst, deg);
    scan1_kernel<<<NB1, 256, 0, stream>>>(deg, rowstart, bsum);
    scan2_kernel<<<1, 512, 0, stream>>>(bsum);
    scan3_kernel<<<NB1, 256, 0, stream>>>(rowstart, bsum);
    hipMemsetAsync(deg, 0, NN * sizeof(int), stream);   // -> cursor
    scatter_kernel<<<(ET + 255) / 256, 256, 0, stream>>>(esrc, edst, rowstart, deg, csr_src);

    // ---- layer 1 ----
    t1_mfma_kernel<<<(NRT + 3) / 4, 256, 0, stream>>>(
        x, whi1, wlo1, bl1, br1, xl1h, xr1h);
    gat1_kernel<<<(NN + 3) / 4, 256, 0, stream>>>(
        rowstart, csr_src, xl1h, xr1h, att1, bias1, h1h);

    // ---- layer 2 ----
    t2_mfma_kernel<<<(NRT + 3) / 4, 256, 0, stream>>>(
        h1h, whi2, wlo2, bl2, br2, xl2h, xr2h);
    gat2_kernel<<<(NN + 7) / 8, 256, 0, stream>>>(
        rowstart, csr_src, xl2h, xr2h, att2, h2);

    // ---- pool + head ----
    pool_kernel<<<(NN + 255) / 256, 256, 0, stream>>>(h2, bias2, batch, pool, cnt);
    head_kernel<<<NG, 64, 0, stream>>>(pool, cnt, Wh1, bh1, Wh2, bh2, (float*)d_out);
}